// Round 1
// baseline (2193.839 us; speedup 1.0000x reference)
//
#include <hip/hip_runtime.h>

#define NN 50000
#define EE 600000
#define HH 128
#define EDD 16
#define BB 256
#define LL 5

#define GF_RELU 1
#define GF_VN   2
#define GF_ACC  4

// ---------------- GEMM: out[M,128] = op(A[M,128] @ W[128,128] + bias [+ vn[batch]]) ----------------
// BM=64, BN=128 (full), BK=32. 256 threads, each computes 4 rows x 8 cols.
// Column groups: cA = t_col*4, cB = 64 + t_col*4  (conflict-free LDS reads, coalesced stores).
__global__ __launch_bounds__(256) void gemm_k(
    const float* __restrict__ A, const float* __restrict__ W,
    const float* __restrict__ bias, float* __restrict__ out,
    int M, int flags,
    const float* __restrict__ vn, const int* __restrict__ batch)
{
    __shared__ float As[64 * 36];    // padded leading dim 36 (144B rows, 16B aligned)
    __shared__ float Ws[32 * 128];

    const int tid = threadIdx.x;
    const int t_col = tid & 15;
    const int t_row = tid >> 4;
    const int brow = blockIdx.x * 64;
    const int cA = t_col * 4;
    const int cB = 64 + t_col * 4;
    const int r0 = t_row * 4;

    float acc[4][8];
#pragma unroll
    for (int i = 0; i < 4; ++i)
#pragma unroll
        for (int j = 0; j < 8; ++j) acc[i][j] = 0.f;

    for (int ko = 0; ko < 128; ko += 32) {
        // stage A tile 64x32
#pragma unroll
        for (int t = 0; t < 2; ++t) {
            int li = tid + t * 256;          // 0..511
            int rl = li >> 3, q = li & 7;
            int grow = brow + rl;
            float4 v = make_float4(0.f, 0.f, 0.f, 0.f);
            if (grow < M) v = *(const float4*)(A + (size_t)grow * 128 + ko + q * 4);
            *(float4*)(&As[rl * 36 + q * 4]) = v;
        }
        // stage W tile 32x128
#pragma unroll
        for (int t = 0; t < 4; ++t) {
            int li = tid + t * 256;          // 0..1023
            int kl = li >> 5, c4 = li & 31;
            *(float4*)(&Ws[kl * 128 + c4 * 4]) = *(const float4*)(W + (size_t)(ko + kl) * 128 + c4 * 4);
        }
        __syncthreads();

#pragma unroll
        for (int k4 = 0; k4 < 32; k4 += 4) {
            float4 a4[4];
#pragma unroll
            for (int i = 0; i < 4; ++i) a4[i] = *(const float4*)(&As[(r0 + i) * 36 + k4]);
#pragma unroll
            for (int dk = 0; dk < 4; ++dk) {
                float4 w0 = *(const float4*)(&Ws[(k4 + dk) * 128 + cA]);
                float4 w1 = *(const float4*)(&Ws[(k4 + dk) * 128 + cB]);
#pragma unroll
                for (int i = 0; i < 4; ++i) {
                    float a = (&a4[i].x)[dk];
                    acc[i][0] = fmaf(a, w0.x, acc[i][0]);
                    acc[i][1] = fmaf(a, w0.y, acc[i][1]);
                    acc[i][2] = fmaf(a, w0.z, acc[i][2]);
                    acc[i][3] = fmaf(a, w0.w, acc[i][3]);
                    acc[i][4] = fmaf(a, w1.x, acc[i][4]);
                    acc[i][5] = fmaf(a, w1.y, acc[i][5]);
                    acc[i][6] = fmaf(a, w1.z, acc[i][6]);
                    acc[i][7] = fmaf(a, w1.w, acc[i][7]);
                }
            }
        }
        __syncthreads();
    }

    const float4 b0 = *(const float4*)(bias + cA);
    const float4 b1 = *(const float4*)(bias + cB);
#pragma unroll
    for (int i = 0; i < 4; ++i) {
        int grow = brow + r0 + i;
        if (grow >= M) continue;
        float4 o0 = make_float4(acc[i][0] + b0.x, acc[i][1] + b0.y, acc[i][2] + b0.z, acc[i][3] + b0.w);
        float4 o1 = make_float4(acc[i][4] + b1.x, acc[i][5] + b1.y, acc[i][6] + b1.z, acc[i][7] + b1.w);
        if (flags & GF_VN) {
            int bg = batch[grow];
            const float* vrow = vn + (size_t)bg * 128;
            float4 v0 = *(const float4*)(vrow + cA);
            float4 v1 = *(const float4*)(vrow + cB);
            o0.x += v0.x; o0.y += v0.y; o0.z += v0.z; o0.w += v0.w;
            o1.x += v1.x; o1.y += v1.y; o1.z += v1.z; o1.w += v1.w;
        }
        if (flags & GF_RELU) {
            o0.x = fmaxf(o0.x, 0.f); o0.y = fmaxf(o0.y, 0.f); o0.z = fmaxf(o0.z, 0.f); o0.w = fmaxf(o0.w, 0.f);
            o1.x = fmaxf(o1.x, 0.f); o1.y = fmaxf(o1.y, 0.f); o1.z = fmaxf(o1.z, 0.f); o1.w = fmaxf(o1.w, 0.f);
        }
        float* orow = out + (size_t)grow * 128;
        if (flags & GF_ACC) {
            float4 p0 = *(const float4*)(orow + cA);
            float4 p1 = *(const float4*)(orow + cB);
            o0.x += p0.x; o0.y += p0.y; o0.z += p0.z; o0.w += p0.w;
            o1.x += p1.x; o1.y += p1.y; o1.z += p1.z; o1.w += p1.w;
        }
        *(float4*)(orow + cA) = o0;
        *(float4*)(orow + cB) = o1;
    }
}

// ---------------- Edge aggregation (CSR gather, no atomics) ----------------
// agg[n,j] = sum_{e: dst[e]==n} ( h[src[e],j] + (edge_attr[e,:] @ eW)[j] + eb[j] )
__global__ __launch_bounds__(256) void aggregate_k(
    const float* __restrict__ h, const float* __restrict__ eattr,
    const float* __restrict__ eW, const float* __restrict__ eb,
    const int* __restrict__ src, const int* __restrict__ rowstart,
    const int* __restrict__ csr_eid, float* __restrict__ agg, int n)
{
    __shared__ float eWs[16 * 128];
    __shared__ float ebs[128];
    const int tid = threadIdx.x;
#pragma unroll
    for (int t = 0; t < 2; ++t) {
        int li = (tid + t * 256) * 4;
        *(float4*)(&eWs[li]) = *(const float4*)(eW + li);
    }
    if (tid < 32) *(float4*)(&ebs[tid * 4]) = *(const float4*)(eb + tid * 4);
    __syncthreads();

    const int sub = tid >> 7, j = tid & 127;
    const int node = blockIdx.x * 2 + sub;
    if (node >= n) return;
    const int s = rowstart[node], e = rowstart[node + 1];
    const float* wc = eWs + j;
    float acc = 0.f;
    for (int p = s; p < e; ++p) {
        int eid = csr_eid[p];
        int sn = src[eid];
        const float4* ar = (const float4*)(eattr + (size_t)eid * 16);
        float4 a0 = ar[0], a1 = ar[1], a2 = ar[2], a3 = ar[3];
        float ea = ebs[j];
        ea = fmaf(a0.x, wc[0 * 128], ea);
        ea = fmaf(a0.y, wc[1 * 128], ea);
        ea = fmaf(a0.z, wc[2 * 128], ea);
        ea = fmaf(a0.w, wc[3 * 128], ea);
        ea = fmaf(a1.x, wc[4 * 128], ea);
        ea = fmaf(a1.y, wc[5 * 128], ea);
        ea = fmaf(a1.z, wc[6 * 128], ea);
        ea = fmaf(a1.w, wc[7 * 128], ea);
        ea = fmaf(a2.x, wc[8 * 128], ea);
        ea = fmaf(a2.y, wc[9 * 128], ea);
        ea = fmaf(a2.z, wc[10 * 128], ea);
        ea = fmaf(a2.w, wc[11 * 128], ea);
        ea = fmaf(a3.x, wc[12 * 128], ea);
        ea = fmaf(a3.y, wc[13 * 128], ea);
        ea = fmaf(a3.z, wc[14 * 128], ea);
        ea = fmaf(a3.w, wc[15 * 128], ea);
        acc += h[(size_t)sn * 128 + j] + ea;
    }
    agg[(size_t)node * 128 + j] = acc;
}

// ---------------- Mean pool per graph (batch is sorted -> contiguous ranges) ----------------
__global__ __launch_bounds__(128) void pool_k(const float* __restrict__ x,
    const int* __restrict__ gstart, float* __restrict__ pooled)
{
    const int b = blockIdx.x, j = threadIdx.x;
    const int s = gstart[b], e = gstart[b + 1];
    float acc = 0.f;
    for (int i = s; i < e; ++i) acc += x[(size_t)i * 128 + j];
    float cnt = (float)(e - s);
    if (cnt < 1.f) cnt = 1.f;
    pooled[b * 128 + j] = acc / cnt;
}

// ---------------- Small helpers ----------------
__global__ void hist_k(const int* __restrict__ idx, int n, int* __restrict__ cnt)
{
    int i = blockIdx.x * 256 + threadIdx.x;
    if (i < n) atomicAdd(&cnt[idx[i]], 1);
}

// exclusive scan per 256-block; bsum (optional) gets block totals
__global__ void scan_k(const int* __restrict__ in, int n, int* __restrict__ out, int* __restrict__ bsum)
{
    __shared__ int s[256];
    int gid = blockIdx.x * 256 + threadIdx.x;
    int v = (gid < n) ? in[gid] : 0;
    s[threadIdx.x] = v;
    __syncthreads();
    for (int off = 1; off < 256; off <<= 1) {
        int t = (threadIdx.x >= off) ? s[threadIdx.x - off] : 0;
        __syncthreads();
        s[threadIdx.x] += t;
        __syncthreads();
    }
    int incl = s[threadIdx.x];
    if (gid < n) out[gid] = incl - v;
    if (bsum != nullptr && threadIdx.x == 255) bsum[blockIdx.x] = incl;
}

__global__ void addoff_k(int* __restrict__ data, const int* __restrict__ boff, int n, int total)
{
    int i = blockIdx.x * 256 + threadIdx.x;
    if (i < n) data[i] += boff[blockIdx.x];
    if (i == 0) data[n] = total;
}

__global__ void set_k(int* p, int v) { p[0] = v; }

__global__ void fill_k(const int* __restrict__ dst, int n, int* __restrict__ cursor, int* __restrict__ csr_eid)
{
    int e = blockIdx.x * 256 + threadIdx.x;
    if (e < n) {
        int slot = atomicAdd(&cursor[dst[e]], 1);
        csr_eid[slot] = e;
    }
}

__global__ void vninit_k(const float* __restrict__ vninit, float* __restrict__ vn)
{
    int i = blockIdx.x * 256 + threadIdx.x;
    vn[i] = vninit[i & 127];
}

// ---------------- Launch ----------------
extern "C" void kernel_launch(void* const* d_in, const int* in_sizes, int n_in,
                              void* d_out, int out_size, void* d_ws, size_t ws_size,
                              hipStream_t stream)
{
    (void)in_sizes; (void)n_in; (void)out_size; (void)ws_size;
    const float* x       = (const float*)d_in[0];
    const float* eattr   = (const float*)d_in[1];
    const float* node_W  = (const float*)d_in[2];
    const float* node_b  = (const float*)d_in[3];
    const float* edge_W  = (const float*)d_in[4];
    const float* edge_b  = (const float*)d_in[5];
    const float* mlp1_W  = (const float*)d_in[6];
    const float* mlp1_b  = (const float*)d_in[7];
    const float* mlp2_W  = (const float*)d_in[8];
    const float* mlp2_b  = (const float*)d_in[9];
    const float* vn_w0   = (const float*)d_in[10];
    const float* vn_b0   = (const float*)d_in[11];
    const float* vn_w1   = (const float*)d_in[12];
    const float* vn_b1   = (const float*)d_in[13];
    const float* fc_W    = (const float*)d_in[14];
    const float* fc_b    = (const float*)d_in[15];
    const float* vn_init = (const float*)d_in[16];
    const int*   eidx    = (const int*)d_in[17];
    const int*   batch   = (const int*)d_in[18];
    const int* srcv = eidx;
    const int* dstv = eidx + EE;

    char* wp = (char*)d_ws;
    auto alloc = [&](size_t bytes) -> void* {
        void* p = (void*)wp;
        wp += (bytes + 255) & ~(size_t)255;
        return p;
    };
    float* x_cur  = (float*)alloc((size_t)NN * HH * 4);
    float* hbuf   = (float*)alloc((size_t)NN * HH * 4);
    float* agg    = (float*)alloc((size_t)NN * HH * 4);
    float* vn     = (float*)alloc((size_t)BB * HH * 4);
    float* vtmp   = (float*)alloc((size_t)BB * HH * 4);
    float* pooled = (float*)alloc((size_t)BB * HH * 4);
    int* deg      = (int*)alloc((size_t)NN * 4);
    int* rowstart = (int*)alloc((size_t)(NN + 1) * 4);
    int* cursor   = (int*)alloc((size_t)NN * 4);
    int* csr_eid  = (int*)alloc((size_t)EE * 4);
    int* bsum     = (int*)alloc(256 * 4);
    int* boff     = (int*)alloc(256 * 4);
    int* gcount   = (int*)alloc((size_t)BB * 4);
    int* gstart   = (int*)alloc((size_t)(BB + 1) * 4);

    hipMemsetAsync(deg, 0, (size_t)NN * 4, stream);
    hipMemsetAsync(gcount, 0, (size_t)BB * 4, stream);

    hist_k<<<(EE + 255) / 256, 256, 0, stream>>>(dstv, EE, deg);
    hist_k<<<(NN + 255) / 256, 256, 0, stream>>>(batch, NN, gcount);

    const int NB1 = (NN + 255) / 256;   // 196
    scan_k<<<NB1, 256, 0, stream>>>(deg, NN, rowstart, bsum);
    scan_k<<<1, 256, 0, stream>>>(bsum, NB1, boff, nullptr);
    addoff_k<<<NB1, 256, 0, stream>>>(rowstart, boff, NN, EE);
    hipMemcpyAsync(cursor, rowstart, (size_t)NN * 4, hipMemcpyDeviceToDevice, stream);
    fill_k<<<(EE + 255) / 256, 256, 0, stream>>>(dstv, EE, cursor, csr_eid);

    scan_k<<<1, 256, 0, stream>>>(gcount, BB, gstart, nullptr);
    set_k<<<1, 1, 0, stream>>>(gstart + BB, NN);

    vninit_k<<<(BB * HH) / 256, 256, 0, stream>>>(vn_init, vn);

    const int GN = (NN + 63) / 64;  // 782
    const int GB = (BB + 63) / 64;  // 4
    const float* xin = x;
    for (int l = 0; l < LL; ++l) {
        gemm_k<<<GN, 256, 0, stream>>>(xin, node_W + (size_t)l * HH * HH, node_b + (size_t)l * HH,
                                       hbuf, NN, GF_VN, vn, batch);
        aggregate_k<<<(NN + 1) / 2, 256, 0, stream>>>(hbuf, eattr, edge_W + (size_t)l * EDD * HH,
                                                      edge_b + (size_t)l * HH, srcv, rowstart, csr_eid, agg, NN);
        gemm_k<<<GN, 256, 0, stream>>>(agg, mlp1_W + (size_t)l * HH * HH, mlp1_b + (size_t)l * HH,
                                       hbuf, NN, GF_RELU, nullptr, nullptr);
        gemm_k<<<GN, 256, 0, stream>>>(hbuf, mlp2_W + (size_t)l * HH * HH, mlp2_b + (size_t)l * HH,
                                       x_cur, NN, GF_RELU, nullptr, nullptr);
        pool_k<<<BB, 128, 0, stream>>>(x_cur, gstart, pooled);
        gemm_k<<<GB, 256, 0, stream>>>(pooled, vn_w0, vn_b0, vtmp, BB, GF_RELU, nullptr, nullptr);
        gemm_k<<<GB, 256, 0, stream>>>(vtmp, vn_w1, vn_b1, vn, BB, GF_RELU | GF_ACC, nullptr, nullptr);
        xin = x_cur;
    }
    pool_k<<<BB, 128, 0, stream>>>(x_cur, gstart, pooled);
    gemm_k<<<GB, 256, 0, stream>>>(pooled, fc_W, fc_b, (float*)d_out, BB, 0, nullptr, nullptr);
}

// Round 2
// 1180.705 us; speedup vs baseline: 1.8581x; 1.8581x over previous
//
#include <hip/hip_runtime.h>

#define NN 50000
#define EE 600000
#define HH 128
#define EDD 16
#define BB 256
#define LL 5

#define GF_RELU 1
#define GF_VN   2
#define GF_ACC  4

// ---------------- GEMM: out[M,128] = op(A[M,128] @ W[128,128] + bias [+ vn[batch]]) ----------------
__global__ __launch_bounds__(256) void gemm_k(
    const float* __restrict__ A, const float* __restrict__ W,
    const float* __restrict__ bias, float* __restrict__ out,
    int M, int flags,
    const float* __restrict__ vn, const int* __restrict__ batch)
{
    __shared__ float As[64 * 36];
    __shared__ float Ws[32 * 128];

    const int tid = threadIdx.x;
    const int t_col = tid & 15;
    const int t_row = tid >> 4;
    const int brow = blockIdx.x * 64;
    const int cA = t_col * 4;
    const int cB = 64 + t_col * 4;
    const int r0 = t_row * 4;

    float acc[4][8];
#pragma unroll
    for (int i = 0; i < 4; ++i)
#pragma unroll
        for (int j = 0; j < 8; ++j) acc[i][j] = 0.f;

    for (int ko = 0; ko < 128; ko += 32) {
#pragma unroll
        for (int t = 0; t < 2; ++t) {
            int li = tid + t * 256;
            int rl = li >> 3, q = li & 7;
            int grow = brow + rl;
            float4 v = make_float4(0.f, 0.f, 0.f, 0.f);
            if (grow < M) v = *(const float4*)(A + (size_t)grow * 128 + ko + q * 4);
            *(float4*)(&As[rl * 36 + q * 4]) = v;
        }
#pragma unroll
        for (int t = 0; t < 4; ++t) {
            int li = tid + t * 256;
            int kl = li >> 5, c4 = li & 31;
            *(float4*)(&Ws[kl * 128 + c4 * 4]) = *(const float4*)(W + (size_t)(ko + kl) * 128 + c4 * 4);
        }
        __syncthreads();

#pragma unroll
        for (int k4 = 0; k4 < 32; k4 += 4) {
            float4 a4[4];
#pragma unroll
            for (int i = 0; i < 4; ++i) a4[i] = *(const float4*)(&As[(r0 + i) * 36 + k4]);
#pragma unroll
            for (int dk = 0; dk < 4; ++dk) {
                float4 w0 = *(const float4*)(&Ws[(k4 + dk) * 128 + cA]);
                float4 w1 = *(const float4*)(&Ws[(k4 + dk) * 128 + cB]);
#pragma unroll
                for (int i = 0; i < 4; ++i) {
                    float a = (&a4[i].x)[dk];
                    acc[i][0] = fmaf(a, w0.x, acc[i][0]);
                    acc[i][1] = fmaf(a, w0.y, acc[i][1]);
                    acc[i][2] = fmaf(a, w0.z, acc[i][2]);
                    acc[i][3] = fmaf(a, w0.w, acc[i][3]);
                    acc[i][4] = fmaf(a, w1.x, acc[i][4]);
                    acc[i][5] = fmaf(a, w1.y, acc[i][5]);
                    acc[i][6] = fmaf(a, w1.z, acc[i][6]);
                    acc[i][7] = fmaf(a, w1.w, acc[i][7]);
                }
            }
        }
        __syncthreads();
    }

    const float4 b0 = *(const float4*)(bias + cA);
    const float4 b1 = *(const float4*)(bias + cB);
#pragma unroll
    for (int i = 0; i < 4; ++i) {
        int grow = brow + r0 + i;
        if (grow >= M) continue;
        float4 o0 = make_float4(acc[i][0] + b0.x, acc[i][1] + b0.y, acc[i][2] + b0.z, acc[i][3] + b0.w);
        float4 o1 = make_float4(acc[i][4] + b1.x, acc[i][5] + b1.y, acc[i][6] + b1.z, acc[i][7] + b1.w);
        if (flags & GF_VN) {
            int bg = batch[grow];
            const float* vrow = vn + (size_t)bg * 128;
            float4 v0 = *(const float4*)(vrow + cA);
            float4 v1 = *(const float4*)(vrow + cB);
            o0.x += v0.x; o0.y += v0.y; o0.z += v0.z; o0.w += v0.w;
            o1.x += v1.x; o1.y += v1.y; o1.z += v1.z; o1.w += v1.w;
        }
        if (flags & GF_RELU) {
            o0.x = fmaxf(o0.x, 0.f); o0.y = fmaxf(o0.y, 0.f); o0.z = fmaxf(o0.z, 0.f); o0.w = fmaxf(o0.w, 0.f);
            o1.x = fmaxf(o1.x, 0.f); o1.y = fmaxf(o1.y, 0.f); o1.z = fmaxf(o1.z, 0.f); o1.w = fmaxf(o1.w, 0.f);
        }
        float* orow = out + (size_t)grow * 128;
        if (flags & GF_ACC) {
            float4 p0 = *(const float4*)(orow + cA);
            float4 p1 = *(const float4*)(orow + cB);
            o0.x += p0.x; o0.y += p0.y; o0.z += p0.z; o0.w += p0.w;
            o1.x += p1.x; o1.y += p1.y; o1.z += p1.z; o1.w += p1.w;
        }
        *(float4*)(orow + cA) = o0;
        *(float4*)(orow + cB) = o1;
    }
}

// ---------------- Edge aggregation v2: pure gather-sum + per-node edge term ----------------
// agg[n,:] = sum_p h[csr_src[p],:]  +  aggE[n,:16] @ eW  +  deg[n]*eb
// 8 nodes/block, 32 lanes/node, float4 per lane. 4 gathers in flight per thread.
__global__ __launch_bounds__(256) void aggregate_k(
    const float* __restrict__ h, const float* __restrict__ aggE,
    const float* __restrict__ eW, const float* __restrict__ eb,
    const int* __restrict__ rowstart, const int* __restrict__ csr_src,
    float* __restrict__ agg, int n)
{
    __shared__ float eWs[16 * 128];
    __shared__ float ebs[128];
    const int tid = threadIdx.x;
#pragma unroll
    for (int t = 0; t < 2; ++t) {
        int li = (tid + t * 256) * 4;
        *(float4*)(&eWs[li]) = *(const float4*)(eW + li);
    }
    if (tid < 32) *(float4*)(&ebs[tid * 4]) = *(const float4*)(eb + tid * 4);
    __syncthreads();

    const int lane = tid & 31;
    const int node = blockIdx.x * 8 + (tid >> 5);
    if (node >= n) return;
    const int s = rowstart[node], e = rowstart[node + 1];
    const float4* h4 = (const float4*)h;

    float4 acc = make_float4(0.f, 0.f, 0.f, 0.f);
    int p = s;
    for (; p + 4 <= e; p += 4) {
        int s0 = csr_src[p], s1 = csr_src[p + 1], s2 = csr_src[p + 2], s3 = csr_src[p + 3];
        float4 v0 = h4[(size_t)s0 * 32 + lane];
        float4 v1 = h4[(size_t)s1 * 32 + lane];
        float4 v2 = h4[(size_t)s2 * 32 + lane];
        float4 v3 = h4[(size_t)s3 * 32 + lane];
        acc.x += v0.x + v1.x + v2.x + v3.x;
        acc.y += v0.y + v1.y + v2.y + v3.y;
        acc.z += v0.z + v1.z + v2.z + v3.z;
        acc.w += v0.w + v1.w + v2.w + v3.w;
    }
    for (; p < e; ++p) {
        float4 v = h4[(size_t)csr_src[p] * 32 + lane];
        acc.x += v.x; acc.y += v.y; acc.z += v.z; acc.w += v.w;
    }

    // per-node edge term: aggE[n] @ eW + deg*eb
    const float degf = (float)(e - s);
    const float* ae = aggE + (size_t)node * 16;
    const float4 b4 = *(const float4*)(&ebs[lane * 4]);
    float4 et = make_float4(degf * b4.x, degf * b4.y, degf * b4.z, degf * b4.w);
#pragma unroll
    for (int k = 0; k < 16; ++k) {
        float a = ae[k];
        float4 w = *(const float4*)(&eWs[k * 128 + lane * 4]);
        et.x = fmaf(a, w.x, et.x);
        et.y = fmaf(a, w.y, et.y);
        et.z = fmaf(a, w.z, et.z);
        et.w = fmaf(a, w.w, et.w);
    }
    acc.x += et.x; acc.y += et.y; acc.z += et.z; acc.w += et.w;
    ((float4*)agg)[(size_t)node * 32 + lane] = acc;
}

// ---------------- Precompute aggE[n,16] = sum of eattr over in-edges ----------------
__global__ __launch_bounds__(256) void aggE_k(
    const float* __restrict__ eattr, const int* __restrict__ rowstart,
    const int* __restrict__ csr_eid, float* __restrict__ aggE, int n)
{
    const int lane = threadIdx.x & 15;
    const int node = blockIdx.x * 16 + (threadIdx.x >> 4);
    if (node >= n) return;
    const int s = rowstart[node], e = rowstart[node + 1];
    float acc = 0.f;
    for (int p = s; p < e; ++p)
        acc += eattr[(size_t)csr_eid[p] * 16 + lane];
    aggE[(size_t)node * 16 + lane] = acc;
}

// ---------------- Mean pool per graph (float4, 4-row-parallel) ----------------
__global__ __launch_bounds__(128) void pool_k(const float* __restrict__ x,
    const int* __restrict__ gstart, float* __restrict__ pooled)
{
    __shared__ float4 red[128];
    const int b = blockIdx.x, t = threadIdx.x;
    const int c = t & 31, r = t >> 5;
    const int s = gstart[b], e = gstart[b + 1];
    const float4* x4 = (const float4*)x;
    float4 acc = make_float4(0.f, 0.f, 0.f, 0.f);
    for (int i = s + r; i < e; i += 4) {
        float4 v = x4[(size_t)i * 32 + c];
        acc.x += v.x; acc.y += v.y; acc.z += v.z; acc.w += v.w;
    }
    red[t] = acc;
    __syncthreads();
    if (t < 32) {
        float4 a0 = red[t], a1 = red[t + 32], a2 = red[t + 64], a3 = red[t + 96];
        float cnt = (float)(e - s);
        if (cnt < 1.f) cnt = 1.f;
        float inv = 1.f / cnt;
        float4 o;
        o.x = (a0.x + a1.x + a2.x + a3.x) * inv;
        o.y = (a0.y + a1.y + a2.y + a3.y) * inv;
        o.z = (a0.z + a1.z + a2.z + a3.z) * inv;
        o.w = (a0.w + a1.w + a2.w + a3.w) * inv;
        ((float4*)pooled)[b * 32 + t] = o;
    }
}

// ---------------- Small helpers ----------------
__global__ void hist_k(const int* __restrict__ idx, int n, int* __restrict__ cnt)
{
    int i = blockIdx.x * 256 + threadIdx.x;
    if (i < n) atomicAdd(&cnt[idx[i]], 1);
}

__global__ void scan_k(const int* __restrict__ in, int n, int* __restrict__ out, int* __restrict__ bsum)
{
    __shared__ int s[256];
    int gid = blockIdx.x * 256 + threadIdx.x;
    int v = (gid < n) ? in[gid] : 0;
    s[threadIdx.x] = v;
    __syncthreads();
    for (int off = 1; off < 256; off <<= 1) {
        int t = (threadIdx.x >= off) ? s[threadIdx.x - off] : 0;
        __syncthreads();
        s[threadIdx.x] += t;
        __syncthreads();
    }
    int incl = s[threadIdx.x];
    if (gid < n) out[gid] = incl - v;
    if (bsum != nullptr && threadIdx.x == 255) bsum[blockIdx.x] = incl;
}

__global__ void addoff_k(int* __restrict__ data, const int* __restrict__ boff, int n, int total)
{
    int i = blockIdx.x * 256 + threadIdx.x;
    if (i < n) data[i] += boff[blockIdx.x];
    if (i == 0) data[n] = total;
}

__global__ void set_k(int* p, int v) { p[0] = v; }

__global__ void fill_k(const int* __restrict__ dst, const int* __restrict__ src, int n,
                       int* __restrict__ cursor, int* __restrict__ csr_eid, int* __restrict__ csr_src)
{
    int e = blockIdx.x * 256 + threadIdx.x;
    if (e < n) {
        int slot = atomicAdd(&cursor[dst[e]], 1);
        csr_eid[slot] = e;
        csr_src[slot] = src[e];
    }
}

__global__ void vninit_k(const float* __restrict__ vninit, float* __restrict__ vn)
{
    int i = blockIdx.x * 256 + threadIdx.x;
    vn[i] = vninit[i & 127];
}

// ---------------- Launch ----------------
extern "C" void kernel_launch(void* const* d_in, const int* in_sizes, int n_in,
                              void* d_out, int out_size, void* d_ws, size_t ws_size,
                              hipStream_t stream)
{
    (void)in_sizes; (void)n_in; (void)out_size; (void)ws_size;
    const float* x       = (const float*)d_in[0];
    const float* eattr   = (const float*)d_in[1];
    const float* node_W  = (const float*)d_in[2];
    const float* node_b  = (const float*)d_in[3];
    const float* edge_W  = (const float*)d_in[4];
    const float* edge_b  = (const float*)d_in[5];
    const float* mlp1_W  = (const float*)d_in[6];
    const float* mlp1_b  = (const float*)d_in[7];
    const float* mlp2_W  = (const float*)d_in[8];
    const float* mlp2_b  = (const float*)d_in[9];
    const float* vn_w0   = (const float*)d_in[10];
    const float* vn_b0   = (const float*)d_in[11];
    const float* vn_w1   = (const float*)d_in[12];
    const float* vn_b1   = (const float*)d_in[13];
    const float* fc_W    = (const float*)d_in[14];
    const float* fc_b    = (const float*)d_in[15];
    const float* vn_init = (const float*)d_in[16];
    const int*   eidx    = (const int*)d_in[17];
    const int*   batch   = (const int*)d_in[18];
    const int* srcv = eidx;
    const int* dstv = eidx + EE;

    char* wp = (char*)d_ws;
    auto alloc = [&](size_t bytes) -> void* {
        void* p = (void*)wp;
        wp += (bytes + 255) & ~(size_t)255;
        return p;
    };
    float* x_cur  = (float*)alloc((size_t)NN * HH * 4);
    float* hbuf   = (float*)alloc((size_t)NN * HH * 4);
    float* agg    = (float*)alloc((size_t)NN * HH * 4);
    float* aggE   = (float*)alloc((size_t)NN * EDD * 4);
    float* vn     = (float*)alloc((size_t)BB * HH * 4);
    float* vtmp   = (float*)alloc((size_t)BB * HH * 4);
    float* pooled = (float*)alloc((size_t)BB * HH * 4);
    int* deg      = (int*)alloc((size_t)NN * 4);
    int* rowstart = (int*)alloc((size_t)(NN + 1) * 4);
    int* cursor   = (int*)alloc((size_t)NN * 4);
    int* csr_eid  = (int*)alloc((size_t)EE * 4);
    int* csr_src  = (int*)alloc((size_t)EE * 4);
    int* bsum     = (int*)alloc(256 * 4);
    int* boff     = (int*)alloc(256 * 4);
    int* gcount   = (int*)alloc((size_t)BB * 4);
    int* gstart   = (int*)alloc((size_t)(BB + 1) * 4);

    hipMemsetAsync(deg, 0, (size_t)NN * 4, stream);
    hipMemsetAsync(gcount, 0, (size_t)BB * 4, stream);

    hist_k<<<(EE + 255) / 256, 256, 0, stream>>>(dstv, EE, deg);
    hist_k<<<(NN + 255) / 256, 256, 0, stream>>>(batch, NN, gcount);

    const int NB1 = (NN + 255) / 256;
    scan_k<<<NB1, 256, 0, stream>>>(deg, NN, rowstart, bsum);
    scan_k<<<1, 256, 0, stream>>>(bsum, NB1, boff, nullptr);
    addoff_k<<<NB1, 256, 0, stream>>>(rowstart, boff, NN, EE);
    hipMemcpyAsync(cursor, rowstart, (size_t)NN * 4, hipMemcpyDeviceToDevice, stream);
    fill_k<<<(EE + 255) / 256, 256, 0, stream>>>(dstv, srcv, EE, cursor, csr_eid, csr_src);

    scan_k<<<1, 256, 0, stream>>>(gcount, BB, gstart, nullptr);
    set_k<<<1, 1, 0, stream>>>(gstart + BB, NN);

    aggE_k<<<(NN + 15) / 16, 256, 0, stream>>>(eattr, rowstart, csr_eid, aggE, NN);
    vninit_k<<<(BB * HH) / 256, 256, 0, stream>>>(vn_init, vn);

    const int GN = (NN + 63) / 64;
    const int GB = (BB + 63) / 64;
    const float* xin = x;
    for (int l = 0; l < LL; ++l) {
        gemm_k<<<GN, 256, 0, stream>>>(xin, node_W + (size_t)l * HH * HH, node_b + (size_t)l * HH,
                                       hbuf, NN, GF_VN, vn, batch);
        aggregate_k<<<(NN + 7) / 8, 256, 0, stream>>>(hbuf, aggE, edge_W + (size_t)l * EDD * HH,
                                                      edge_b + (size_t)l * HH, rowstart, csr_src, agg, NN);
        gemm_k<<<GN, 256, 0, stream>>>(agg, mlp1_W + (size_t)l * HH * HH, mlp1_b + (size_t)l * HH,
                                       hbuf, NN, GF_RELU, nullptr, nullptr);
        gemm_k<<<GN, 256, 0, stream>>>(hbuf, mlp2_W + (size_t)l * HH * HH, mlp2_b + (size_t)l * HH,
                                       x_cur, NN, GF_RELU, nullptr, nullptr);
        pool_k<<<BB, 128, 0, stream>>>(x_cur, gstart, pooled);
        gemm_k<<<GB, 256, 0, stream>>>(pooled, vn_w0, vn_b0, vtmp, BB, GF_RELU, nullptr, nullptr);
        gemm_k<<<GB, 256, 0, stream>>>(vtmp, vn_w1, vn_b1, vn, BB, GF_RELU | GF_ACC, nullptr, nullptr);
        xin = x_cur;
    }
    pool_k<<<BB, 128, 0, stream>>>(x_cur, gstart, pooled);
    gemm_k<<<GB, 256, 0, stream>>>(pooled, fc_W, fc_b, (float*)d_out, BB, 0, nullptr, nullptr);
}

// Round 3
// 1161.276 us; speedup vs baseline: 1.8892x; 1.0167x over previous
//
#include <hip/hip_runtime.h>

#define NN 50000
#define EE 600000
#define HH 128
#define EDD 16
#define BB 256
#define LL 5
#define NN16 (NN * 16)

#define GF_RELU 1
#define GF_VN   2
#define GF_ACC  4

typedef short s16x8 __attribute__((ext_vector_type(8)));
typedef float f32x4 __attribute__((ext_vector_type(4)));

__device__ inline short f2bf(float f) {
    unsigned u = __float_as_uint(f);
    u += 0x7fff + ((u >> 16) & 1);
    return (short)(u >> 16);
}
__device__ inline float bf2f(short s) {
    return __uint_as_float(((unsigned)(unsigned short)s) << 16);
}

// ---------------- Weight prep: W[mat][k][n] fp32 -> Wh/Wl[mat][n][k] bf16 (hi/lo split) ----------------
__global__ __launch_bounds__(256) void wprep_k(const float* __restrict__ W,
    short* __restrict__ Wh, short* __restrict__ Wl, int total)
{
    int idx = blockIdx.x * 256 + threadIdx.x;
    if (idx >= total) return;
    int mat = idx >> 14;
    int r = idx & 16383;
    int n = r >> 7, k = r & 127;
    float w = W[(mat << 14) + (k << 7) + n];
    short h = f2bf(w);
    short l = f2bf(w - bf2f(h));
    Wh[idx] = h; Wl[idx] = l;
}

// ---------------- MFMA GEMM: out[M,128] = op(A[M,128] @ W + bias [+vn]) ----------------
// Block 256 = 4 waves (2x2). M-tile 64. Split bf16: 3 MFMAs per tile-kstep.
// A staged fp32->bf16 hi/lo in LDS (row stride 136 shorts); B frags from global (L2-hot).
__global__ __launch_bounds__(256) void gemm_mfma_k(
    const float* __restrict__ A, const short* __restrict__ Wh, const short* __restrict__ Wl,
    const float* __restrict__ bias, float* __restrict__ out, int M, int flags,
    const float* __restrict__ vn, const int* __restrict__ batch)
{
    __shared__ short Ahs[64 * 136];
    __shared__ short Als[64 * 136];
    const int tid = threadIdx.x;
    const int brow = blockIdx.x * 64;

    // ---- stage A tile: 64x128 fp32 -> bf16 hi/lo ----
    {
        const int r = tid >> 2, cg = tid & 3;
        const int grow = brow + r;
        short* ph = &Ahs[r * 136 + cg * 32];
        short* pl = &Als[r * 136 + cg * 32];
        if (grow < M) {
            const float4* src = (const float4*)(A + (size_t)grow * 128 + cg * 32);
#pragma unroll
            for (int i = 0; i < 8; ++i) {
                float4 v = src[i];
                short4 h, l;
                h.x = f2bf(v.x); l.x = f2bf(v.x - bf2f(h.x));
                h.y = f2bf(v.y); l.y = f2bf(v.y - bf2f(h.y));
                h.z = f2bf(v.z); l.z = f2bf(v.z - bf2f(h.z));
                h.w = f2bf(v.w); l.w = f2bf(v.w - bf2f(h.w));
                ((short4*)ph)[i] = h;
                ((short4*)pl)[i] = l;
            }
        } else {
            short4 z = make_short4(0, 0, 0, 0);
#pragma unroll
            for (int i = 0; i < 8; ++i) { ((short4*)ph)[i] = z; ((short4*)pl)[i] = z; }
        }
    }
    __syncthreads();

    const int lane = tid & 63;
    const int wv = tid >> 6;
    const int wm = wv & 1, wn = wv >> 1;
    const int m0 = wm * 32, n0 = wn * 64;
    const int lm = lane & 15, quad = lane >> 4;

    f32x4 acc[2][4];
#pragma unroll
    for (int mt = 0; mt < 2; ++mt)
#pragma unroll
        for (int nt = 0; nt < 4; ++nt) acc[mt][nt] = (f32x4)(0.f);

    const short* whbase = Wh + ((size_t)(n0 + lm) << 7) + quad * 8;
    const short* wlbase = Wl + ((size_t)(n0 + lm) << 7) + quad * 8;

#pragma unroll
    for (int ks = 0; ks < 4; ++ks) {
        s16x8 Bh[4], Bl[4], Afh[2], Afl[2];
#pragma unroll
        for (int nt = 0; nt < 4; ++nt) {
            Bh[nt] = *(const s16x8*)(whbase + (nt << 11) + ks * 32);
            Bl[nt] = *(const s16x8*)(wlbase + (nt << 11) + ks * 32);
        }
#pragma unroll
        for (int mt = 0; mt < 2; ++mt) {
            int ro = (m0 + mt * 16 + lm) * 136 + ks * 32 + quad * 8;
            Afh[mt] = *(const s16x8*)(&Ahs[ro]);
            Afl[mt] = *(const s16x8*)(&Als[ro]);
        }
#pragma unroll
        for (int mt = 0; mt < 2; ++mt)
#pragma unroll
            for (int nt = 0; nt < 4; ++nt) {
                acc[mt][nt] = __builtin_amdgcn_mfma_f32_16x16x32_bf16(Afh[mt], Bh[nt], acc[mt][nt], 0, 0, 0);
                acc[mt][nt] = __builtin_amdgcn_mfma_f32_16x16x32_bf16(Afh[mt], Bl[nt], acc[mt][nt], 0, 0, 0);
                acc[mt][nt] = __builtin_amdgcn_mfma_f32_16x16x32_bf16(Afl[mt], Bh[nt], acc[mt][nt], 0, 0, 0);
            }
    }

    // ---- epilogue: C/D layout col=lane&15, row=quad*4+reg ----
    const int col = n0 + lm;
#pragma unroll
    for (int mt = 0; mt < 2; ++mt) {
        int rbase = brow + m0 + mt * 16 + quad * 4;
#pragma unroll
        for (int r = 0; r < 4; ++r) {
            int grow = rbase + r;
            if (grow >= M) continue;
            float* orow = out + (size_t)grow * 128;
            const float* vrow = nullptr;
            if (flags & GF_VN) vrow = vn + (size_t)batch[grow] * 128;
#pragma unroll
            for (int nt = 0; nt < 4; ++nt) {
                float v = acc[mt][nt][r] + bias[col + nt * 16];
                if (flags & GF_VN) v += vrow[col + nt * 16];
                if (flags & GF_RELU) v = fmaxf(v, 0.f);
                if (flags & GF_ACC) v += orow[col + nt * 16];
                orow[col + nt * 16] = v;
            }
        }
    }
}

// ---------------- Edge aggregation: pure gather-sum + per-node edge term ----------------
__global__ __launch_bounds__(256) void aggregate_k(
    const float* __restrict__ h, const float* __restrict__ aggE,
    const float* __restrict__ eW, const float* __restrict__ eb,
    const int* __restrict__ rowstart, const int* __restrict__ csr_src,
    float* __restrict__ agg, int n)
{
    __shared__ float eWs[16 * 128];
    __shared__ float ebs[128];
    const int tid = threadIdx.x;
#pragma unroll
    for (int t = 0; t < 2; ++t) {
        int li = (tid + t * 256) * 4;
        *(float4*)(&eWs[li]) = *(const float4*)(eW + li);
    }
    if (tid < 32) *(float4*)(&ebs[tid * 4]) = *(const float4*)(eb + tid * 4);
    __syncthreads();

    const int lane = tid & 31;
    const int node = blockIdx.x * 8 + (tid >> 5);
    if (node >= n) return;
    const int s = rowstart[node], e = rowstart[node + 1];
    const float4* h4 = (const float4*)h;

    float4 acc = make_float4(0.f, 0.f, 0.f, 0.f);
    int p = s;
    for (; p + 4 <= e; p += 4) {
        int s0 = csr_src[p], s1 = csr_src[p + 1], s2 = csr_src[p + 2], s3 = csr_src[p + 3];
        float4 v0 = h4[(size_t)s0 * 32 + lane];
        float4 v1 = h4[(size_t)s1 * 32 + lane];
        float4 v2 = h4[(size_t)s2 * 32 + lane];
        float4 v3 = h4[(size_t)s3 * 32 + lane];
        acc.x += v0.x + v1.x + v2.x + v3.x;
        acc.y += v0.y + v1.y + v2.y + v3.y;
        acc.z += v0.z + v1.z + v2.z + v3.z;
        acc.w += v0.w + v1.w + v2.w + v3.w;
    }
    for (; p < e; ++p) {
        float4 v = h4[(size_t)csr_src[p] * 32 + lane];
        acc.x += v.x; acc.y += v.y; acc.z += v.z; acc.w += v.w;
    }

    const float degf = (float)(e - s);
    const float* ae = aggE + (size_t)node * 16;
    const float4 b4 = *(const float4*)(&ebs[lane * 4]);
    float4 et = make_float4(degf * b4.x, degf * b4.y, degf * b4.z, degf * b4.w);
#pragma unroll
    for (int k = 0; k < 16; ++k) {
        float a = ae[k];
        float4 w = *(const float4*)(&eWs[k * 128 + lane * 4]);
        et.x = fmaf(a, w.x, et.x);
        et.y = fmaf(a, w.y, et.y);
        et.z = fmaf(a, w.z, et.z);
        et.w = fmaf(a, w.w, et.w);
    }
    acc.x += et.x; acc.y += et.y; acc.z += et.z; acc.w += et.w;
    ((float4*)agg)[(size_t)node * 32 + lane] = acc;
}

// ---------------- aggE[n,16] = sum of eattr over in-edges ----------------
__global__ __launch_bounds__(256) void aggE_k(
    const float* __restrict__ eattr, const int* __restrict__ rowstart,
    const int* __restrict__ csr_eid, float* __restrict__ aggE, int n)
{
    const int lane = threadIdx.x & 15;
    const int node = blockIdx.x * 16 + (threadIdx.x >> 4);
    if (node >= n) return;
    const int s = rowstart[node], e = rowstart[node + 1];
    float acc = 0.f;
    for (int p = s; p < e; ++p)
        acc += eattr[(size_t)csr_eid[p] * 16 + lane];
    aggE[(size_t)node * 16 + lane] = acc;
}

// ---------------- Mean pool per graph ----------------
__global__ __launch_bounds__(128) void pool_k(const float* __restrict__ x,
    const int* __restrict__ gstart, float* __restrict__ pooled)
{
    __shared__ float4 red[128];
    const int b = blockIdx.x, t = threadIdx.x;
    const int c = t & 31, r = t >> 5;
    const int s = gstart[b], e = gstart[b + 1];
    const float4* x4 = (const float4*)x;
    float4 acc = make_float4(0.f, 0.f, 0.f, 0.f);
    for (int i = s + r; i < e; i += 4) {
        float4 v = x4[(size_t)i * 32 + c];
        acc.x += v.x; acc.y += v.y; acc.z += v.z; acc.w += v.w;
    }
    red[t] = acc;
    __syncthreads();
    if (t < 32) {
        float4 a0 = red[t], a1 = red[t + 32], a2 = red[t + 64], a3 = red[t + 96];
        float cnt = (float)(e - s);
        if (cnt < 1.f) cnt = 1.f;
        float inv = 1.f / cnt;
        float4 o;
        o.x = (a0.x + a1.x + a2.x + a3.x) * inv;
        o.y = (a0.y + a1.y + a2.y + a3.y) * inv;
        o.z = (a0.z + a1.z + a2.z + a3.z) * inv;
        o.w = (a0.w + a1.w + a2.w + a3.w) * inv;
        ((float4*)pooled)[b * 32 + t] = o;
    }
}

// ---------------- CSR build helpers (padded + shadowed atomics) ----------------
__global__ void histp_k(const int* __restrict__ idx, int n, int* __restrict__ cntp)
{
    int i = blockIdx.x * 256 + threadIdx.x;
    if (i < n) atomicAdd(&cntp[(blockIdx.x & 3) * NN16 + (idx[i] << 4)], 1);
}

__global__ void scan_deg_k(const int* __restrict__ degp, int n, int* __restrict__ out, int* __restrict__ bsum)
{
    __shared__ int s[256];
    int gid = blockIdx.x * 256 + threadIdx.x;
    int v = 0;
    if (gid < n) {
        int o = gid << 4;
        v = degp[o] + degp[NN16 + o] + degp[2 * NN16 + o] + degp[3 * NN16 + o];
    }
    s[threadIdx.x] = v;
    __syncthreads();
    for (int off = 1; off < 256; off <<= 1) {
        int t = (threadIdx.x >= off) ? s[threadIdx.x - off] : 0;
        __syncthreads();
        s[threadIdx.x] += t;
        __syncthreads();
    }
    int incl = s[threadIdx.x];
    if (gid < n) out[gid] = incl - v;
    if (bsum != nullptr && threadIdx.x == 255) bsum[blockIdx.x] = incl;
}

__global__ void scan_k(const int* __restrict__ in, int n, int* __restrict__ out, int* __restrict__ bsum)
{
    __shared__ int s[256];
    int gid = blockIdx.x * 256 + threadIdx.x;
    int v = (gid < n) ? in[gid] : 0;
    s[threadIdx.x] = v;
    __syncthreads();
    for (int off = 1; off < 256; off <<= 1) {
        int t = (threadIdx.x >= off) ? s[threadIdx.x - off] : 0;
        __syncthreads();
        s[threadIdx.x] += t;
        __syncthreads();
    }
    int incl = s[threadIdx.x];
    if (gid < n) out[gid] = incl - v;
    if (bsum != nullptr && threadIdx.x == 255) bsum[blockIdx.x] = incl;
}

__global__ void addoff_k(int* __restrict__ data, const int* __restrict__ boff, int n, int total)
{
    int i = blockIdx.x * 256 + threadIdx.x;
    if (i < n) data[i] += boff[blockIdx.x];
    if (i == 0) data[n] = total;
}

__global__ void curinit_k(const int* __restrict__ rowstart, int* __restrict__ cursorp)
{
    int i = blockIdx.x * 256 + threadIdx.x;
    if (i < NN) cursorp[i << 4] = rowstart[i];
}

__global__ void fill_k(const int* __restrict__ dst, const int* __restrict__ src, int n,
                       int* __restrict__ cursorp, int* __restrict__ csr_eid, int* __restrict__ csr_src)
{
    int e = blockIdx.x * 256 + threadIdx.x;
    if (e < n) {
        int slot = atomicAdd(&cursorp[dst[e] << 4], 1);
        csr_eid[slot] = e;
        csr_src[slot] = src[e];
    }
}

// batch is sorted: gstart via binary search, no atomics
__global__ void gstart_k(const int* __restrict__ batch, int* __restrict__ gstart)
{
    int b = blockIdx.x * 64 + threadIdx.x;
    if (b > BB) return;
    if (b == BB) { gstart[BB] = NN; return; }
    int lo = 0, hi = NN;
    while (lo < hi) {
        int mid = (lo + hi) >> 1;
        if (batch[mid] < b) lo = mid + 1; else hi = mid;
    }
    gstart[b] = lo;
}

__global__ void vninit_k(const float* __restrict__ vninit, float* __restrict__ vn)
{
    int i = blockIdx.x * 256 + threadIdx.x;
    vn[i] = vninit[i & 127];
}

// ---------------- Launch ----------------
extern "C" void kernel_launch(void* const* d_in, const int* in_sizes, int n_in,
                              void* d_out, int out_size, void* d_ws, size_t ws_size,
                              hipStream_t stream)
{
    (void)in_sizes; (void)n_in; (void)out_size; (void)ws_size;
    const float* x       = (const float*)d_in[0];
    const float* eattr   = (const float*)d_in[1];
    const float* node_W  = (const float*)d_in[2];
    const float* node_b  = (const float*)d_in[3];
    const float* edge_W  = (const float*)d_in[4];
    const float* edge_b  = (const float*)d_in[5];
    const float* mlp1_W  = (const float*)d_in[6];
    const float* mlp1_b  = (const float*)d_in[7];
    const float* mlp2_W  = (const float*)d_in[8];
    const float* mlp2_b  = (const float*)d_in[9];
    const float* vn_w0   = (const float*)d_in[10];
    const float* vn_b0   = (const float*)d_in[11];
    const float* vn_w1   = (const float*)d_in[12];
    const float* vn_b1   = (const float*)d_in[13];
    const float* fc_W    = (const float*)d_in[14];
    const float* fc_b    = (const float*)d_in[15];
    const float* vn_init = (const float*)d_in[16];
    const int*   eidx    = (const int*)d_in[17];
    const int*   batch   = (const int*)d_in[18];
    const int* srcv = eidx;
    const int* dstv = eidx + EE;

    char* wp = (char*)d_ws;
    auto alloc = [&](size_t bytes) -> void* {
        void* p = (void*)wp;
        wp += (bytes + 255) & ~(size_t)255;
        return p;
    };
    float* x_cur  = (float*)alloc((size_t)NN * HH * 4);
    float* hbuf   = (float*)alloc((size_t)NN * HH * 4);
    float* agg    = (float*)alloc((size_t)NN * HH * 4);
    float* aggE   = (float*)alloc((size_t)NN * EDD * 4);
    float* vn     = (float*)alloc((size_t)BB * HH * 4);
    float* vtmp   = (float*)alloc((size_t)BB * HH * 4);
    float* pooled = (float*)alloc((size_t)BB * HH * 4);
    int* degp     = (int*)alloc((size_t)4 * NN16 * 4);
    int* rowstart = (int*)alloc((size_t)(NN + 1) * 4);
    int* cursorp  = (int*)alloc((size_t)NN16 * 4);
    int* csr_eid  = (int*)alloc((size_t)EE * 4);
    int* csr_src  = (int*)alloc((size_t)EE * 4);
    int* bsum     = (int*)alloc(256 * 4);
    int* boff     = (int*)alloc(256 * 4);
    int* gstart   = (int*)alloc((size_t)(BB + 1) * 4);
    // split weights: 15 layer mats + vn_w0 + vn_w1 + fc
    short* WtN_h  = (short*)alloc((size_t)5 * 16384 * 2);
    short* WtN_l  = (short*)alloc((size_t)5 * 16384 * 2);
    short* Wt1_h  = (short*)alloc((size_t)5 * 16384 * 2);
    short* Wt1_l  = (short*)alloc((size_t)5 * 16384 * 2);
    short* Wt2_h  = (short*)alloc((size_t)5 * 16384 * 2);
    short* Wt2_l  = (short*)alloc((size_t)5 * 16384 * 2);
    short* Wv0_h  = (short*)alloc((size_t)16384 * 2);
    short* Wv0_l  = (short*)alloc((size_t)16384 * 2);
    short* Wv1_h  = (short*)alloc((size_t)16384 * 2);
    short* Wv1_l  = (short*)alloc((size_t)16384 * 2);
    short* Wfc_h  = (short*)alloc((size_t)16384 * 2);
    short* Wfc_l  = (short*)alloc((size_t)16384 * 2);

    hipMemsetAsync(degp, 0, (size_t)4 * NN16 * 4, stream);

    histp_k<<<(EE + 255) / 256, 256, 0, stream>>>(dstv, EE, degp);

    const int NB1 = (NN + 255) / 256;
    scan_deg_k<<<NB1, 256, 0, stream>>>(degp, NN, rowstart, bsum);
    scan_k<<<1, 256, 0, stream>>>(bsum, NB1, boff, nullptr);
    addoff_k<<<NB1, 256, 0, stream>>>(rowstart, boff, NN, EE);
    curinit_k<<<NB1, 256, 0, stream>>>(rowstart, cursorp);
    fill_k<<<(EE + 255) / 256, 256, 0, stream>>>(dstv, srcv, EE, cursorp, csr_eid, csr_src);

    gstart_k<<<5, 64, 0, stream>>>(batch, gstart);

    aggE_k<<<(NN + 15) / 16, 256, 0, stream>>>(eattr, rowstart, csr_eid, aggE, NN);
    vninit_k<<<(BB * HH) / 256, 256, 0, stream>>>(vn_init, vn);

    // weight splits
    wprep_k<<<(5 * 16384 + 255) / 256, 256, 0, stream>>>(node_W, WtN_h, WtN_l, 5 * 16384);
    wprep_k<<<(5 * 16384 + 255) / 256, 256, 0, stream>>>(mlp1_W, Wt1_h, Wt1_l, 5 * 16384);
    wprep_k<<<(5 * 16384 + 255) / 256, 256, 0, stream>>>(mlp2_W, Wt2_h, Wt2_l, 5 * 16384);
    wprep_k<<<64, 256, 0, stream>>>(vn_w0, Wv0_h, Wv0_l, 16384);
    wprep_k<<<64, 256, 0, stream>>>(vn_w1, Wv1_h, Wv1_l, 16384);
    wprep_k<<<64, 256, 0, stream>>>(fc_W, Wfc_h, Wfc_l, 16384);

    const int GN = (NN + 63) / 64;
    const int GB = (BB + 63) / 64;
    const float* xin = x;
    for (int l = 0; l < LL; ++l) {
        gemm_mfma_k<<<GN, 256, 0, stream>>>(xin, WtN_h + (size_t)l * 16384, WtN_l + (size_t)l * 16384,
                                            node_b + (size_t)l * HH, hbuf, NN, GF_VN, vn, batch);
        aggregate_k<<<(NN + 7) / 8, 256, 0, stream>>>(hbuf, aggE, edge_W + (size_t)l * EDD * HH,
                                                      edge_b + (size_t)l * HH, rowstart, csr_src, agg, NN);
        gemm_mfma_k<<<GN, 256, 0, stream>>>(agg, Wt1_h + (size_t)l * 16384, Wt1_l + (size_t)l * 16384,
                                            mlp1_b + (size_t)l * HH, hbuf, NN, GF_RELU, nullptr, nullptr);
        gemm_mfma_k<<<GN, 256, 0, stream>>>(hbuf, Wt2_h + (size_t)l * 16384, Wt2_l + (size_t)l * 16384,
                                            mlp2_b + (size_t)l * HH, x_cur, NN, GF_RELU, nullptr, nullptr);
        pool_k<<<BB, 128, 0, stream>>>(x_cur, gstart, pooled);
        gemm_mfma_k<<<GB, 256, 0, stream>>>(pooled, Wv0_h, Wv0_l, vn_b0, vtmp, BB, GF_RELU, nullptr, nullptr);
        gemm_mfma_k<<<GB, 256, 0, stream>>>(vtmp, Wv1_h, Wv1_l, vn_b1, vn, BB, GF_RELU | GF_ACC, nullptr, nullptr);
        xin = x_cur;
    }
    pool_k<<<BB, 128, 0, stream>>>(x_cur, gstart, pooled);
    gemm_mfma_k<<<GB, 256, 0, stream>>>(pooled, Wfc_h, Wfc_l, fc_b, (float*)d_out, BB, 0, nullptr, nullptr);
}

// Round 4
// 813.641 us; speedup vs baseline: 2.6963x; 1.4273x over previous
//
#include <hip/hip_runtime.h>

#define NN 50000
#define EE 600000
#define HH 128
#define EDD 16
#define BB 256
#define LL 5
#define NN16 (NN * 16)

typedef short s16x8 __attribute__((ext_vector_type(8)));
typedef float f32x4 __attribute__((ext_vector_type(4)));

__device__ __forceinline__ short f2bf(float f) {
    unsigned u = __float_as_uint(f);
    u += 0x7fff + ((u >> 16) & 1);
    return (short)(u >> 16);
}
__device__ __forceinline__ float bf2f(short s) {
    return __uint_as_float(((unsigned)(unsigned short)s) << 16);
}

// ---------------- Weight prep: W[mat][k][n] fp32 -> frag-ordered bf16 hi/lo ----------------
// frag order: idx = ((ntw*4 + ks)*64 + lane)*8 + j ; ntw = wn*2+nt ; lane = quad*16+lm
// n = wn*32 + nt*16 + lm ; k = ks*32 + quad*8 + j  -> wave B-loads are 1KB contiguous.
__global__ __launch_bounds__(256) void wprep_k(const float* __restrict__ W,
    short* __restrict__ Wh, short* __restrict__ Wl, int total)
{
    int idx = blockIdx.x * 256 + threadIdx.x;
    if (idx >= total) return;
    int mat = idx >> 14;
    int r = idx & 16383;
    int j = r & 7, lane = (r >> 3) & 63, ks = (r >> 9) & 3, ntw = (r >> 11) & 7;
    int lm = lane & 15, quad = lane >> 4;
    int n = (ntw >> 1) * 32 + (ntw & 1) * 16 + lm;
    int k = ks * 32 + quad * 8 + j;
    float w = W[(mat << 14) + (k << 7) + n];
    short h = f2bf(w);
    Wh[idx] = h;
    Wl[idx] = f2bf(w - bf2f(h));
}

// ---------------- shared helpers ----------------
__device__ __forceinline__ void stage_A(const float* __restrict__ A, int M, int brow,
    int tid, short* __restrict__ Ah, short* __restrict__ Al)
{
    const int r = tid >> 2, cg = tid & 3;
    const int grow = brow + r;
    short* ph = Ah + r * 136 + cg * 32;
    short* pl = Al + r * 136 + cg * 32;
    if (grow < M) {
        const float4* src = (const float4*)(A + (size_t)grow * 128 + cg * 32);
#pragma unroll
        for (int i = 0; i < 8; ++i) {
            float4 v = src[i];
            short4 h, l;
            h.x = f2bf(v.x); l.x = f2bf(v.x - bf2f(h.x));
            h.y = f2bf(v.y); l.y = f2bf(v.y - bf2f(h.y));
            h.z = f2bf(v.z); l.z = f2bf(v.z - bf2f(h.z));
            h.w = f2bf(v.w); l.w = f2bf(v.w - bf2f(h.w));
            ((short4*)ph)[i] = h;
            ((short4*)pl)[i] = l;
        }
    } else {
        short4 z = make_short4(0, 0, 0, 0);
#pragma unroll
        for (int i = 0; i < 8; ++i) { ((short4*)ph)[i] = z; ((short4*)pl)[i] = z; }
    }
}

// one full K=128 pass: acc[mt][nt] += A(LDS) x W(frag-ordered global, L2-hot)
__device__ __forceinline__ void mfma_stage(
    const short* __restrict__ Ah, const short* __restrict__ Al,
    const short* __restrict__ Wh, const short* __restrict__ Wl,
    int wn, int lm, int quad, int lane, f32x4 acc[4][2])
{
    s16x8 Bh[2][4], Bl[2][4];
#pragma unroll
    for (int nt = 0; nt < 2; ++nt)
#pragma unroll
        for (int ks = 0; ks < 4; ++ks) {
            int fi = ((((wn * 2 + nt) * 4) + ks) * 64 + lane) * 8;
            Bh[nt][ks] = *(const s16x8*)(Wh + fi);
            Bl[nt][ks] = *(const s16x8*)(Wl + fi);
        }
#pragma unroll
    for (int ks = 0; ks < 4; ++ks) {
        s16x8 ah[4], al[4];
#pragma unroll
        for (int mt = 0; mt < 4; ++mt) {
            int off = (mt * 16 + lm) * 136 + ks * 32 + quad * 8;
            ah[mt] = *(const s16x8*)(Ah + off);
            al[mt] = *(const s16x8*)(Al + off);
        }
#pragma unroll
        for (int mt = 0; mt < 4; ++mt)
#pragma unroll
            for (int nt = 0; nt < 2; ++nt) {
                acc[mt][nt] = __builtin_amdgcn_mfma_f32_16x16x32_bf16(ah[mt], Bh[nt][ks], acc[mt][nt], 0, 0, 0);
                acc[mt][nt] = __builtin_amdgcn_mfma_f32_16x16x32_bf16(ah[mt], Bl[nt][ks], acc[mt][nt], 0, 0, 0);
                acc[mt][nt] = __builtin_amdgcn_mfma_f32_16x16x32_bf16(al[mt], Bh[nt][ks], acc[mt][nt], 0, 0, 0);
            }
    }
}

__device__ __forceinline__ void store_out(const float* __restrict__ Fo,
    float* __restrict__ out, int M, int brow, int tid)
{
    const int r = tid >> 2, cg = tid & 3;
    const int grow = brow + r;
    if (grow >= M) return;
    const float4* src = (const float4*)(Fo + r * 132 + cg * 32);
    float4* dst = (float4*)(out + (size_t)grow * 128 + cg * 32);
#pragma unroll
    for (int i = 0; i < 8; ++i) dst[i] = src[i];
}

// ---------------- node encode: out = A @ W + b + vn[batch] ----------------
__global__ __launch_bounds__(256) void gemm_node_k(
    const float* __restrict__ A, const short* __restrict__ Wh, const short* __restrict__ Wl,
    const float* __restrict__ bias, float* __restrict__ out, int M,
    const float* __restrict__ vn, const int* __restrict__ batch)
{
    __shared__ __align__(16) char smraw[64 * 136 * 2 * 2];
    short* Ah = (short*)smraw;
    short* Al = Ah + 64 * 136;
    float* Fo = (float*)smraw;
    const int tid = threadIdx.x, brow = blockIdx.x * 64;

    stage_A(A, M, brow, tid, Ah, Al);
    __syncthreads();

    const int lane = tid & 63, wn = tid >> 6, lm = lane & 15, quad = lane >> 4;
    f32x4 acc[4][2];
#pragma unroll
    for (int mt = 0; mt < 4; ++mt) { acc[mt][0] = (f32x4)(0.f); acc[mt][1] = (f32x4)(0.f); }
    mfma_stage(Ah, Al, Wh, Wl, wn, lm, quad, lane, acc);
    __syncthreads();   // all A reads done before LDS reuse

    const int colb = wn * 32 + lm;
    const float b0 = bias[colb], b1 = bias[colb + 16];
#pragma unroll
    for (int mt = 0; mt < 4; ++mt) {
#pragma unroll
        for (int r = 0; r < 4; ++r) {
            int trow = mt * 16 + quad * 4 + r;
            int grow = brow + trow;
            int bg = batch[grow < M ? grow : M - 1];
            const float* vrow = vn + (size_t)bg * 128;
            Fo[trow * 132 + colb]      = acc[mt][0][r] + b0 + vrow[colb];
            Fo[trow * 132 + colb + 16] = acc[mt][1][r] + b1 + vrow[colb + 16];
        }
    }
    __syncthreads();
    store_out(Fo, out, M, brow, tid);
}

// ---------------- fused MLP: out = relu(relu(A@W1+b1)@W2+b2) ----------------
__global__ __launch_bounds__(256) void gemm_mlp_k(
    const float* __restrict__ A,
    const short* __restrict__ W1h, const short* __restrict__ W1l, const float* __restrict__ b1,
    const short* __restrict__ W2h, const short* __restrict__ W2l, const float* __restrict__ b2,
    float* __restrict__ out, int M)
{
    __shared__ __align__(16) char smraw[64 * 136 * 2 * 2];
    short* Ah = (short*)smraw;
    short* Al = Ah + 64 * 136;
    float* Fo = (float*)smraw;
    const int tid = threadIdx.x, brow = blockIdx.x * 64;

    stage_A(A, M, brow, tid, Ah, Al);
    __syncthreads();

    const int lane = tid & 63, wn = tid >> 6, lm = lane & 15, quad = lane >> 4;
    const int colb = wn * 32 + lm;

    f32x4 acc[4][2];
#pragma unroll
    for (int mt = 0; mt < 4; ++mt) { acc[mt][0] = (f32x4)(0.f); acc[mt][1] = (f32x4)(0.f); }
    mfma_stage(Ah, Al, W1h, W1l, wn, lm, quad, lane, acc);
    __syncthreads();   // all stage-1 A reads done

    // epilogue-1: bias+relu, split to bf16 hi/lo, back into the A tile
    {
        const float c0 = b1[colb], c1 = b1[colb + 16];
#pragma unroll
        for (int mt = 0; mt < 4; ++mt) {
#pragma unroll
            for (int r = 0; r < 4; ++r) {
                int trow = mt * 16 + quad * 4 + r;
                float v0 = fmaxf(acc[mt][0][r] + c0, 0.f);
                float v1 = fmaxf(acc[mt][1][r] + c1, 0.f);
                short h0 = f2bf(v0), h1 = f2bf(v1);
                Ah[trow * 136 + colb]      = h0;
                Ah[trow * 136 + colb + 16] = h1;
                Al[trow * 136 + colb]      = f2bf(v0 - bf2f(h0));
                Al[trow * 136 + colb + 16] = f2bf(v1 - bf2f(h1));
            }
        }
    }
    __syncthreads();

#pragma unroll
    for (int mt = 0; mt < 4; ++mt) { acc[mt][0] = (f32x4)(0.f); acc[mt][1] = (f32x4)(0.f); }
    mfma_stage(Ah, Al, W2h, W2l, wn, lm, quad, lane, acc);
    __syncthreads();

    const float d0 = b2[colb], d1 = b2[colb + 16];
#pragma unroll
    for (int mt = 0; mt < 4; ++mt) {
#pragma unroll
        for (int r = 0; r < 4; ++r) {
            int trow = mt * 16 + quad * 4 + r;
            Fo[trow * 132 + colb]      = fmaxf(acc[mt][0][r] + d0, 0.f);
            Fo[trow * 132 + colb + 16] = fmaxf(acc[mt][1][r] + d1, 0.f);
        }
    }
    __syncthreads();
    store_out(Fo, out, M, brow, tid);
}

// ---------------- Edge aggregation: pure gather-sum + per-node edge term ----------------
__global__ __launch_bounds__(256) void aggregate_k(
    const float* __restrict__ h, const float* __restrict__ aggE,
    const float* __restrict__ eW, const float* __restrict__ eb,
    const int* __restrict__ rowstart, const int* __restrict__ csr_src,
    float* __restrict__ agg, int n)
{
    __shared__ float eWs[16 * 128];
    __shared__ float ebs[128];
    const int tid = threadIdx.x;
#pragma unroll
    for (int t = 0; t < 2; ++t) {
        int li = (tid + t * 256) * 4;
        *(float4*)(&eWs[li]) = *(const float4*)(eW + li);
    }
    if (tid < 32) *(float4*)(&ebs[tid * 4]) = *(const float4*)(eb + tid * 4);
    __syncthreads();

    const int lane = tid & 31;
    const int node = blockIdx.x * 8 + (tid >> 5);
    if (node >= n) return;
    const int s = rowstart[node], e = rowstart[node + 1];
    const float4* h4 = (const float4*)h;

    float4 acc = make_float4(0.f, 0.f, 0.f, 0.f);
    int p = s;
    for (; p + 4 <= e; p += 4) {
        int s0 = csr_src[p], s1 = csr_src[p + 1], s2 = csr_src[p + 2], s3 = csr_src[p + 3];
        float4 v0 = h4[(size_t)s0 * 32 + lane];
        float4 v1 = h4[(size_t)s1 * 32 + lane];
        float4 v2 = h4[(size_t)s2 * 32 + lane];
        float4 v3 = h4[(size_t)s3 * 32 + lane];
        acc.x += v0.x + v1.x + v2.x + v3.x;
        acc.y += v0.y + v1.y + v2.y + v3.y;
        acc.z += v0.z + v1.z + v2.z + v3.z;
        acc.w += v0.w + v1.w + v2.w + v3.w;
    }
    for (; p < e; ++p) {
        float4 v = h4[(size_t)csr_src[p] * 32 + lane];
        acc.x += v.x; acc.y += v.y; acc.z += v.z; acc.w += v.w;
    }

    const float degf = (float)(e - s);
    const float* ae = aggE + (size_t)node * 16;
    const float4 b4 = *(const float4*)(&ebs[lane * 4]);
    float4 et = make_float4(degf * b4.x, degf * b4.y, degf * b4.z, degf * b4.w);
#pragma unroll
    for (int k = 0; k < 16; ++k) {
        float a = ae[k];
        float4 w = *(const float4*)(&eWs[k * 128 + lane * 4]);
        et.x = fmaf(a, w.x, et.x);
        et.y = fmaf(a, w.y, et.y);
        et.z = fmaf(a, w.z, et.z);
        et.w = fmaf(a, w.w, et.w);
    }
    acc.x += et.x; acc.y += et.y; acc.z += et.z; acc.w += et.w;
    ((float4*)agg)[(size_t)node * 32 + lane] = acc;
}

// ---------------- aggE[n,16] = sum of eattr over in-edges ----------------
__global__ __launch_bounds__(256) void aggE_k(
    const float* __restrict__ eattr, const int* __restrict__ rowstart,
    const int* __restrict__ csr_eid, float* __restrict__ aggE, int n)
{
    const int lane = threadIdx.x & 15;
    const int node = blockIdx.x * 16 + (threadIdx.x >> 4);
    if (node >= n) return;
    const int s = rowstart[node], e = rowstart[node + 1];
    float acc = 0.f;
    for (int p = s; p < e; ++p)
        acc += eattr[(size_t)csr_eid[p] * 16 + lane];
    aggE[(size_t)node * 16 + lane] = acc;
}

// ---------------- fused pool + VN MLP: vn += relu(relu(pool@W0+b0)@W1+b1) ----------------
__global__ __launch_bounds__(128) void poolvn_k(
    const float* __restrict__ x, const int* __restrict__ gstart,
    const float* __restrict__ W0, const float* __restrict__ b0,
    const float* __restrict__ W1, const float* __restrict__ b1,
    float* __restrict__ vn)
{
    __shared__ float4 red[128];
    __shared__ float p[128], q[128];
    const int g = blockIdx.x, t = threadIdx.x;
    const int c = t & 31, rr = t >> 5;
    const int s = gstart[g], e = gstart[g + 1];
    const float4* x4 = (const float4*)x;
    float4 a = make_float4(0.f, 0.f, 0.f, 0.f);
    for (int i = s + rr; i < e; i += 4) {
        float4 v = x4[(size_t)i * 32 + c];
        a.x += v.x; a.y += v.y; a.z += v.z; a.w += v.w;
    }
    red[t] = a;
    __syncthreads();
    if (t < 32) {
        float4 a0 = red[t], a1 = red[t + 32], a2 = red[t + 64], a3 = red[t + 96];
        float cnt = (float)(e - s);
        if (cnt < 1.f) cnt = 1.f;
        float inv = 1.f / cnt;
        float4 o;
        o.x = (a0.x + a1.x + a2.x + a3.x) * inv;
        o.y = (a0.y + a1.y + a2.y + a3.y) * inv;
        o.z = (a0.z + a1.z + a2.z + a3.z) * inv;
        o.w = (a0.w + a1.w + a2.w + a3.w) * inv;
        ((float4*)p)[t] = o;
    }
    __syncthreads();
    float acc0 = b0[t];
    for (int k = 0; k < 128; ++k) acc0 = fmaf(p[k], W0[k * 128 + t], acc0);
    q[t] = fmaxf(acc0, 0.f);
    __syncthreads();
    float acc1 = b1[t];
    for (int k = 0; k < 128; ++k) acc1 = fmaf(q[k], W1[k * 128 + t], acc1);
    vn[g * 128 + t] += fmaxf(acc1, 0.f);
}

// ---------------- fused final pool + classifier ----------------
__global__ __launch_bounds__(128) void poolfc_k(
    const float* __restrict__ x, const int* __restrict__ gstart,
    const float* __restrict__ W, const float* __restrict__ b,
    float* __restrict__ out)
{
    __shared__ float4 red[128];
    __shared__ float p[128];
    const int g = blockIdx.x, t = threadIdx.x;
    const int c = t & 31, rr = t >> 5;
    const int s = gstart[g], e = gstart[g + 1];
    const float4* x4 = (const float4*)x;
    float4 a = make_float4(0.f, 0.f, 0.f, 0.f);
    for (int i = s + rr; i < e; i += 4) {
        float4 v = x4[(size_t)i * 32 + c];
        a.x += v.x; a.y += v.y; a.z += v.z; a.w += v.w;
    }
    red[t] = a;
    __syncthreads();
    if (t < 32) {
        float4 a0 = red[t], a1 = red[t + 32], a2 = red[t + 64], a3 = red[t + 96];
        float cnt = (float)(e - s);
        if (cnt < 1.f) cnt = 1.f;
        float inv = 1.f / cnt;
        float4 o;
        o.x = (a0.x + a1.x + a2.x + a3.x) * inv;
        o.y = (a0.y + a1.y + a2.y + a3.y) * inv;
        o.z = (a0.z + a1.z + a2.z + a3.z) * inv;
        o.w = (a0.w + a1.w + a2.w + a3.w) * inv;
        ((float4*)p)[t] = o;
    }
    __syncthreads();
    float acc = b[t];
    for (int k = 0; k < 128; ++k) acc = fmaf(p[k], W[k * 128 + t], acc);
    out[g * 128 + t] = acc;
}

// ---------------- CSR build helpers ----------------
__global__ void histp_k(const int* __restrict__ idx, int n, int* __restrict__ cntp)
{
    int i = blockIdx.x * 256 + threadIdx.x;
    if (i < n) atomicAdd(&cntp[(blockIdx.x & 3) * NN16 + (idx[i] << 4)], 1);
}

__global__ void scan_deg_k(const int* __restrict__ degp, int n, int* __restrict__ out, int* __restrict__ bsum)
{
    __shared__ int s[256];
    int gid = blockIdx.x * 256 + threadIdx.x;
    int v = 0;
    if (gid < n) {
        int o = gid << 4;
        v = degp[o] + degp[NN16 + o] + degp[2 * NN16 + o] + degp[3 * NN16 + o];
    }
    s[threadIdx.x] = v;
    __syncthreads();
    for (int off = 1; off < 256; off <<= 1) {
        int t = (threadIdx.x >= off) ? s[threadIdx.x - off] : 0;
        __syncthreads();
        s[threadIdx.x] += t;
        __syncthreads();
    }
    int incl = s[threadIdx.x];
    if (gid < n) out[gid] = incl - v;
    if (bsum != nullptr && threadIdx.x == 255) bsum[blockIdx.x] = incl;
}

__global__ void scan_k(const int* __restrict__ in, int n, int* __restrict__ out, int* __restrict__ bsum)
{
    __shared__ int s[256];
    int gid = blockIdx.x * 256 + threadIdx.x;
    int v = (gid < n) ? in[gid] : 0;
    s[threadIdx.x] = v;
    __syncthreads();
    for (int off = 1; off < 256; off <<= 1) {
        int t = (threadIdx.x >= off) ? s[threadIdx.x - off] : 0;
        __syncthreads();
        s[threadIdx.x] += t;
        __syncthreads();
    }
    int incl = s[threadIdx.x];
    if (gid < n) out[gid] = incl - v;
    if (bsum != nullptr && threadIdx.x == 255) bsum[blockIdx.x] = incl;
}

__global__ void addoff_k(int* __restrict__ data, const int* __restrict__ boff, int n, int total)
{
    int i = blockIdx.x * 256 + threadIdx.x;
    if (i < n) data[i] += boff[blockIdx.x];
    if (i == 0) data[n] = total;
}

__global__ void curinit_k(const int* __restrict__ rowstart, int* __restrict__ cursorp)
{
    int i = blockIdx.x * 256 + threadIdx.x;
    if (i < NN) cursorp[i << 4] = rowstart[i];
}

__global__ void fill_k(const int* __restrict__ dst, const int* __restrict__ src, int n,
                       int* __restrict__ cursorp, int* __restrict__ csr_eid, int* __restrict__ csr_src)
{
    int e = blockIdx.x * 256 + threadIdx.x;
    if (e < n) {
        int slot = atomicAdd(&cursorp[dst[e] << 4], 1);
        csr_eid[slot] = e;
        csr_src[slot] = src[e];
    }
}

__global__ void gstart_k(const int* __restrict__ batch, int* __restrict__ gstart)
{
    int b = blockIdx.x * 64 + threadIdx.x;
    if (b > BB) return;
    if (b == BB) { gstart[BB] = NN; return; }
    int lo = 0, hi = NN;
    while (lo < hi) {
        int mid = (lo + hi) >> 1;
        if (batch[mid] < b) lo = mid + 1; else hi = mid;
    }
    gstart[b] = lo;
}

__global__ void vninit_k(const float* __restrict__ vninit, float* __restrict__ vn)
{
    int i = blockIdx.x * 256 + threadIdx.x;
    vn[i] = vninit[i & 127];
}

// ---------------- Launch ----------------
extern "C" void kernel_launch(void* const* d_in, const int* in_sizes, int n_in,
                              void* d_out, int out_size, void* d_ws, size_t ws_size,
                              hipStream_t stream)
{
    (void)in_sizes; (void)n_in; (void)out_size; (void)ws_size;
    const float* x       = (const float*)d_in[0];
    const float* eattr   = (const float*)d_in[1];
    const float* node_W  = (const float*)d_in[2];
    const float* node_b  = (const float*)d_in[3];
    const float* edge_W  = (const float*)d_in[4];
    const float* edge_b  = (const float*)d_in[5];
    const float* mlp1_W  = (const float*)d_in[6];
    const float* mlp1_b  = (const float*)d_in[7];
    const float* mlp2_W  = (const float*)d_in[8];
    const float* mlp2_b  = (const float*)d_in[9];
    const float* vn_w0   = (const float*)d_in[10];
    const float* vn_b0   = (const float*)d_in[11];
    const float* vn_w1   = (const float*)d_in[12];
    const float* vn_b1   = (const float*)d_in[13];
    const float* fc_W    = (const float*)d_in[14];
    const float* fc_b    = (const float*)d_in[15];
    const float* vn_init = (const float*)d_in[16];
    const int*   eidx    = (const int*)d_in[17];
    const int*   batch   = (const int*)d_in[18];
    const int* srcv = eidx;
    const int* dstv = eidx + EE;

    char* wp = (char*)d_ws;
    auto alloc = [&](size_t bytes) -> void* {
        void* p = (void*)wp;
        wp += (bytes + 255) & ~(size_t)255;
        return p;
    };
    float* x_cur  = (float*)alloc((size_t)NN * HH * 4);
    float* hbuf   = (float*)alloc((size_t)NN * HH * 4);
    float* agg    = (float*)alloc((size_t)NN * HH * 4);
    float* aggE   = (float*)alloc((size_t)NN * EDD * 4);
    float* vn     = (float*)alloc((size_t)BB * HH * 4);
    int* degp     = (int*)alloc((size_t)4 * NN16 * 4);
    int* rowstart = (int*)alloc((size_t)(NN + 1) * 4);
    int* cursorp  = (int*)alloc((size_t)NN16 * 4);
    int* csr_eid  = (int*)alloc((size_t)EE * 4);
    int* csr_src  = (int*)alloc((size_t)EE * 4);
    int* bsum     = (int*)alloc(256 * 4);
    int* boff     = (int*)alloc(256 * 4);
    int* gstart   = (int*)alloc((size_t)(BB + 1) * 4);
    short* WtN_h  = (short*)alloc((size_t)5 * 16384 * 2);
    short* WtN_l  = (short*)alloc((size_t)5 * 16384 * 2);
    short* Wt1_h  = (short*)alloc((size_t)5 * 16384 * 2);
    short* Wt1_l  = (short*)alloc((size_t)5 * 16384 * 2);
    short* Wt2_h  = (short*)alloc((size_t)5 * 16384 * 2);
    short* Wt2_l  = (short*)alloc((size_t)5 * 16384 * 2);

    hipMemsetAsync(degp, 0, (size_t)4 * NN16 * 4, stream);

    histp_k<<<(EE + 255) / 256, 256, 0, stream>>>(dstv, EE, degp);

    const int NB1 = (NN + 255) / 256;
    scan_deg_k<<<NB1, 256, 0, stream>>>(degp, NN, rowstart, bsum);
    scan_k<<<1, 256, 0, stream>>>(bsum, NB1, boff, nullptr);
    addoff_k<<<NB1, 256, 0, stream>>>(rowstart, boff, NN, EE);
    curinit_k<<<NB1, 256, 0, stream>>>(rowstart, cursorp);
    fill_k<<<(EE + 255) / 256, 256, 0, stream>>>(dstv, srcv, EE, cursorp, csr_eid, csr_src);

    gstart_k<<<5, 64, 0, stream>>>(batch, gstart);

    aggE_k<<<(NN + 15) / 16, 256, 0, stream>>>(eattr, rowstart, csr_eid, aggE, NN);
    vninit_k<<<(BB * HH) / 256, 256, 0, stream>>>(vn_init, vn);

    wprep_k<<<(5 * 16384 + 255) / 256, 256, 0, stream>>>(node_W, WtN_h, WtN_l, 5 * 16384);
    wprep_k<<<(5 * 16384 + 255) / 256, 256, 0, stream>>>(mlp1_W, Wt1_h, Wt1_l, 5 * 16384);
    wprep_k<<<(5 * 16384 + 255) / 256, 256, 0, stream>>>(mlp2_W, Wt2_h, Wt2_l, 5 * 16384);

    const int GN = (NN + 63) / 64;
    const float* xin = x;
    for (int l = 0; l < LL; ++l) {
        gemm_node_k<<<GN, 256, 0, stream>>>(xin, WtN_h + (size_t)l * 16384, WtN_l + (size_t)l * 16384,
                                            node_b + (size_t)l * HH, hbuf, NN, vn, batch);
        aggregate_k<<<(NN + 7) / 8, 256, 0, stream>>>(hbuf, aggE, edge_W + (size_t)l * EDD * HH,
                                                      edge_b + (size_t)l * HH, rowstart, csr_src, agg, NN);
        gemm_mlp_k<<<GN, 256, 0, stream>>>(agg,
                                           Wt1_h + (size_t)l * 16384, Wt1_l + (size_t)l * 16384, mlp1_b + (size_t)l * HH,
                                           Wt2_h + (size_t)l * 16384, Wt2_l + (size_t)l * 16384, mlp2_b + (size_t)l * HH,
                                           x_cur, NN);
        poolvn_k<<<BB, 128, 0, stream>>>(x_cur, gstart, vn_w0, vn_b0, vn_w1, vn_b1, vn);
        xin = x_cur;
    }
    poolfc_k<<<BB, 128, 0, stream>>>(x_cur, gstart, fc_W, fc_b, (float*)d_out);
}

// Round 5
// 728.585 us; speedup vs baseline: 3.0111x; 1.1167x over previous
//
#include <hip/hip_runtime.h>

#define NN 50000
#define EE 600000
#define HH 128
#define EDD 16
#define BB 256
#define LL 5
#define NN16 (NN * 16)

typedef short s16x8 __attribute__((ext_vector_type(8)));
typedef float f32x4 __attribute__((ext_vector_type(4)));
typedef _Float16 f16x4 __attribute__((ext_vector_type(4)));
typedef _Float16 f16x8 __attribute__((ext_vector_type(8)));

__device__ __forceinline__ short f2bf(float f) {
    unsigned u = __float_as_uint(f);
    u += 0x7fff + ((u >> 16) & 1);
    return (short)(u >> 16);
}
__device__ __forceinline__ float bf2f(short s) {
    return __uint_as_float(((unsigned)(unsigned short)s) << 16);
}

// ---------------- Weight prep: W[mat][k][n] fp32 -> frag-ordered bf16 hi/lo ----------------
__global__ __launch_bounds__(256) void wprep_k(const float* __restrict__ W,
    short* __restrict__ Wh, short* __restrict__ Wl, int total)
{
    int idx = blockIdx.x * 256 + threadIdx.x;
    if (idx >= total) return;
    int mat = idx >> 14;
    int r = idx & 16383;
    int j = r & 7, lane = (r >> 3) & 63, ks = (r >> 9) & 3, ntw = (r >> 11) & 7;
    int lm = lane & 15, quad = lane >> 4;
    int n = (ntw >> 1) * 32 + (ntw & 1) * 16 + lm;
    int k = ks * 32 + quad * 8 + j;
    float w = W[(mat << 14) + (k << 7) + n];
    short h = f2bf(w);
    Wh[idx] = h;
    Wl[idx] = f2bf(w - bf2f(h));
}

// ---------------- x -> hi/lo bf16 planes (one-time) ----------------
__global__ __launch_bounds__(256) void xprep_k(const float* __restrict__ x,
    short* __restrict__ Xh, short* __restrict__ Xl)
{
    int i = blockIdx.x * 256 + threadIdx.x;   // over NN*32 float4s
    if (i >= NN * 32) return;
    float4 v = ((const float4*)x)[i];
    short4 h, l;
    h.x = f2bf(v.x); l.x = f2bf(v.x - bf2f(h.x));
    h.y = f2bf(v.y); l.y = f2bf(v.y - bf2f(h.y));
    h.z = f2bf(v.z); l.z = f2bf(v.z - bf2f(h.z));
    h.w = f2bf(v.w); l.w = f2bf(v.w - bf2f(h.w));
    ((short4*)Xh)[i] = h;
    ((short4*)Xl)[i] = l;
}

// ---------------- shared GEMM helpers ----------------
// stage: copy pre-split hi/lo planes into padded LDS tiles (pure copy, no VALU)
__device__ __forceinline__ void stage_A_bf(const short* __restrict__ Ah_g,
    const short* __restrict__ Al_g, int M, int brow, int tid,
    short* __restrict__ Ah, short* __restrict__ Al)
{
    const int r = tid >> 2, cg = tid & 3;
    const int grow = brow + r;
    short* ph = Ah + r * 136 + cg * 32;
    short* pl = Al + r * 136 + cg * 32;
    if (grow < M) {
        const s16x8* sh = (const s16x8*)(Ah_g + (size_t)grow * 128 + cg * 32);
        const s16x8* sl = (const s16x8*)(Al_g + (size_t)grow * 128 + cg * 32);
#pragma unroll
        for (int i = 0; i < 4; ++i) { ((s16x8*)ph)[i] = sh[i]; ((s16x8*)pl)[i] = sl[i]; }
    } else {
        s16x8 z = (s16x8)0;
#pragma unroll
        for (int i = 0; i < 4; ++i) { ((s16x8*)ph)[i] = z; ((s16x8*)pl)[i] = z; }
    }
}

// one full K=128 pass: acc[mt][nt] += A(LDS) x W(frag-ordered global, L2-hot)
__device__ __forceinline__ void mfma_stage(
    const short* __restrict__ Ah, const short* __restrict__ Al,
    const short* __restrict__ Wh, const short* __restrict__ Wl,
    int wn, int lm, int quad, int lane, f32x4 acc[4][2])
{
    s16x8 Bh[2][4], Bl[2][4];
#pragma unroll
    for (int nt = 0; nt < 2; ++nt)
#pragma unroll
        for (int ks = 0; ks < 4; ++ks) {
            int fi = ((((wn * 2 + nt) * 4) + ks) * 64 + lane) * 8;
            Bh[nt][ks] = *(const s16x8*)(Wh + fi);
            Bl[nt][ks] = *(const s16x8*)(Wl + fi);
        }
#pragma unroll
    for (int ks = 0; ks < 4; ++ks) {
        s16x8 ah[4], al[4];
#pragma unroll
        for (int mt = 0; mt < 4; ++mt) {
            int off = (mt * 16 + lm) * 136 + ks * 32 + quad * 8;
            ah[mt] = *(const s16x8*)(Ah + off);
            al[mt] = *(const s16x8*)(Al + off);
        }
#pragma unroll
        for (int mt = 0; mt < 4; ++mt)
#pragma unroll
            for (int nt = 0; nt < 2; ++nt) {
                acc[mt][nt] = __builtin_amdgcn_mfma_f32_16x16x32_bf16(ah[mt], Bh[nt][ks], acc[mt][nt], 0, 0, 0);
                acc[mt][nt] = __builtin_amdgcn_mfma_f32_16x16x32_bf16(ah[mt], Bl[nt][ks], acc[mt][nt], 0, 0, 0);
                acc[mt][nt] = __builtin_amdgcn_mfma_f32_16x16x32_bf16(al[mt], Bh[nt][ks], acc[mt][nt], 0, 0, 0);
            }
    }
}

// ---------------- node encode: h16 = A @ W + b + vn[batch]  (fp16 out) ----------------
__global__ __launch_bounds__(256) void gemm_node_k(
    const short* __restrict__ Ah_g, const short* __restrict__ Al_g,
    const short* __restrict__ Wh, const short* __restrict__ Wl,
    const float* __restrict__ bias, _Float16* __restrict__ out, int M,
    const float* __restrict__ vn, const int* __restrict__ batch)
{
    __shared__ __align__(16) char smraw[64 * 136 * 2 * 2];
    short* Ah = (short*)smraw;
    short* Al = Ah + 64 * 136;
    float* Fo = (float*)smraw;
    const int tid = threadIdx.x, brow = blockIdx.x * 64;

    stage_A_bf(Ah_g, Al_g, M, brow, tid, Ah, Al);
    __syncthreads();

    const int lane = tid & 63, wn = tid >> 6, lm = lane & 15, quad = lane >> 4;
    f32x4 acc[4][2];
#pragma unroll
    for (int mt = 0; mt < 4; ++mt) { acc[mt][0] = (f32x4)(0.f); acc[mt][1] = (f32x4)(0.f); }
    mfma_stage(Ah, Al, Wh, Wl, wn, lm, quad, lane, acc);
    __syncthreads();

    const int colb = wn * 32 + lm;
    const float b0 = bias[colb], b1 = bias[colb + 16];
#pragma unroll
    for (int mt = 0; mt < 4; ++mt) {
#pragma unroll
        for (int r = 0; r < 4; ++r) {
            int trow = mt * 16 + quad * 4 + r;
            int grow = brow + trow;
            int bg = batch[grow < M ? grow : M - 1];
            const float* vrow = vn + (size_t)bg * 128;
            Fo[trow * 132 + colb]      = acc[mt][0][r] + b0 + vrow[colb];
            Fo[trow * 132 + colb + 16] = acc[mt][1][r] + b1 + vrow[colb + 16];
        }
    }
    __syncthreads();
    // store fp16
    {
        const int r = tid >> 2, cg = tid & 3;
        const int grow = brow + r;
        if (grow < M) {
            const float* src = Fo + r * 132 + cg * 32;
            _Float16* dst = out + (size_t)grow * 128 + cg * 32;
#pragma unroll
            for (int i = 0; i < 4; ++i) {
                f16x8 v;
#pragma unroll
                for (int j = 0; j < 8; ++j) v[j] = (_Float16)src[i * 8 + j];
                *(f16x8*)(dst + i * 8) = v;
            }
        }
    }
}

// ---------------- fused MLP: X = relu(relu(A@W1+b1)@W2+b2)  (hi/lo out) ----------------
__global__ __launch_bounds__(256) void gemm_mlp_k(
    const short* __restrict__ Agh, const short* __restrict__ Agl,
    const short* __restrict__ W1h, const short* __restrict__ W1l, const float* __restrict__ b1,
    const short* __restrict__ W2h, const short* __restrict__ W2l, const float* __restrict__ b2,
    short* __restrict__ Xh, short* __restrict__ Xl, int M)
{
    __shared__ __align__(16) char smraw[64 * 136 * 2 * 2];
    short* Ah = (short*)smraw;
    short* Al = Ah + 64 * 136;
    float* Fo = (float*)smraw;
    const int tid = threadIdx.x, brow = blockIdx.x * 64;

    stage_A_bf(Agh, Agl, M, brow, tid, Ah, Al);
    __syncthreads();

    const int lane = tid & 63, wn = tid >> 6, lm = lane & 15, quad = lane >> 4;
    const int colb = wn * 32 + lm;

    f32x4 acc[4][2];
#pragma unroll
    for (int mt = 0; mt < 4; ++mt) { acc[mt][0] = (f32x4)(0.f); acc[mt][1] = (f32x4)(0.f); }
    mfma_stage(Ah, Al, W1h, W1l, wn, lm, quad, lane, acc);
    __syncthreads();

    // epilogue-1: bias+relu, split to bf16 hi/lo, back into the A tile
    {
        const float c0 = b1[colb], c1 = b1[colb + 16];
#pragma unroll
        for (int mt = 0; mt < 4; ++mt) {
#pragma unroll
            for (int r = 0; r < 4; ++r) {
                int trow = mt * 16 + quad * 4 + r;
                float v0 = fmaxf(acc[mt][0][r] + c0, 0.f);
                float v1 = fmaxf(acc[mt][1][r] + c1, 0.f);
                short h0 = f2bf(v0), h1 = f2bf(v1);
                Ah[trow * 136 + colb]      = h0;
                Ah[trow * 136 + colb + 16] = h1;
                Al[trow * 136 + colb]      = f2bf(v0 - bf2f(h0));
                Al[trow * 136 + colb + 16] = f2bf(v1 - bf2f(h1));
            }
        }
    }
    __syncthreads();

#pragma unroll
    for (int mt = 0; mt < 4; ++mt) { acc[mt][0] = (f32x4)(0.f); acc[mt][1] = (f32x4)(0.f); }
    mfma_stage(Ah, Al, W2h, W2l, wn, lm, quad, lane, acc);
    __syncthreads();

    const float d0 = b2[colb], d1 = b2[colb + 16];
#pragma unroll
    for (int mt = 0; mt < 4; ++mt) {
#pragma unroll
        for (int r = 0; r < 4; ++r) {
            int trow = mt * 16 + quad * 4 + r;
            Fo[trow * 132 + colb]      = fmaxf(acc[mt][0][r] + d0, 0.f);
            Fo[trow * 132 + colb + 16] = fmaxf(acc[mt][1][r] + d1, 0.f);
        }
    }
    __syncthreads();
    // store hi/lo planes
    {
        const int r = tid >> 2, cg = tid & 3;
        const int grow = brow + r;
        if (grow < M) {
            const float* src = Fo + r * 132 + cg * 32;
            short* dh = Xh + (size_t)grow * 128 + cg * 32;
            short* dl = Xl + (size_t)grow * 128 + cg * 32;
#pragma unroll
            for (int i = 0; i < 4; ++i) {
                s16x8 hv, lv;
#pragma unroll
                for (int j = 0; j < 8; ++j) {
                    float v = src[i * 8 + j];
                    short h = f2bf(v);
                    hv[j] = h;
                    lv[j] = f2bf(v - bf2f(h));
                }
                *(s16x8*)(dh + i * 8) = hv;
                *(s16x8*)(dl + i * 8) = lv;
            }
        }
    }
}

// ---------------- Edge aggregation: fp16 gather-sum + per-node edge term, hi/lo out ----------------
__global__ __launch_bounds__(256) void aggregate_k(
    const _Float16* __restrict__ h, const float* __restrict__ aggE,
    const float* __restrict__ eW, const float* __restrict__ eb,
    const int* __restrict__ rowstart, const int* __restrict__ csr_src,
    short* __restrict__ Agh, short* __restrict__ Agl, int n)
{
    __shared__ float eWs[16 * 128];
    __shared__ float ebs[128];
    const int tid = threadIdx.x;
#pragma unroll
    for (int t = 0; t < 2; ++t) {
        int li = (tid + t * 256) * 4;
        *(float4*)(&eWs[li]) = *(const float4*)(eW + li);
    }
    if (tid < 32) *(float4*)(&ebs[tid * 4]) = *(const float4*)(eb + tid * 4);
    __syncthreads();

    const int lane = tid & 31;
    const int node = blockIdx.x * 8 + (tid >> 5);
    if (node >= n) return;
    const int s = rowstart[node], e = rowstart[node + 1];
    const f16x4* h4 = (const f16x4*)h;

    float4 acc = make_float4(0.f, 0.f, 0.f, 0.f);
    int p = s;
    for (; p + 4 <= e; p += 4) {
        int s0 = csr_src[p], s1 = csr_src[p + 1], s2 = csr_src[p + 2], s3 = csr_src[p + 3];
        f16x4 v0 = h4[(size_t)s0 * 32 + lane];
        f16x4 v1 = h4[(size_t)s1 * 32 + lane];
        f16x4 v2 = h4[(size_t)s2 * 32 + lane];
        f16x4 v3 = h4[(size_t)s3 * 32 + lane];
        acc.x += (float)v0[0] + (float)v1[0] + (float)v2[0] + (float)v3[0];
        acc.y += (float)v0[1] + (float)v1[1] + (float)v2[1] + (float)v3[1];
        acc.z += (float)v0[2] + (float)v1[2] + (float)v2[2] + (float)v3[2];
        acc.w += (float)v0[3] + (float)v1[3] + (float)v2[3] + (float)v3[3];
    }
    for (; p < e; ++p) {
        f16x4 v = h4[(size_t)csr_src[p] * 32 + lane];
        acc.x += (float)v[0]; acc.y += (float)v[1]; acc.z += (float)v[2]; acc.w += (float)v[3];
    }

    const float degf = (float)(e - s);
    const float* ae = aggE + (size_t)node * 16;
    const float4 b4 = *(const float4*)(&ebs[lane * 4]);
    float4 et = make_float4(degf * b4.x, degf * b4.y, degf * b4.z, degf * b4.w);
#pragma unroll
    for (int k = 0; k < 16; ++k) {
        float a = ae[k];
        float4 w = *(const float4*)(&eWs[k * 128 + lane * 4]);
        et.x = fmaf(a, w.x, et.x);
        et.y = fmaf(a, w.y, et.y);
        et.z = fmaf(a, w.z, et.z);
        et.w = fmaf(a, w.w, et.w);
    }
    acc.x += et.x; acc.y += et.y; acc.z += et.z; acc.w += et.w;

    short4 hs, ls;
    hs.x = f2bf(acc.x); ls.x = f2bf(acc.x - bf2f(hs.x));
    hs.y = f2bf(acc.y); ls.y = f2bf(acc.y - bf2f(hs.y));
    hs.z = f2bf(acc.z); ls.z = f2bf(acc.z - bf2f(hs.z));
    hs.w = f2bf(acc.w); ls.w = f2bf(acc.w - bf2f(hs.w));
    ((short4*)Agh)[(size_t)node * 32 + lane] = hs;
    ((short4*)Agl)[(size_t)node * 32 + lane] = ls;
}

// ---------------- aggE[n,16] = sum of eattr over in-edges ----------------
__global__ __launch_bounds__(256) void aggE_k(
    const float* __restrict__ eattr, const int* __restrict__ rowstart,
    const int* __restrict__ csr_eid, float* __restrict__ aggE, int n)
{
    const int lane = threadIdx.x & 15;
    const int node = blockIdx.x * 16 + (threadIdx.x >> 4);
    if (node >= n) return;
    const int s = rowstart[node], e = rowstart[node + 1];
    float acc = 0.f;
    for (int p = s; p < e; ++p)
        acc += eattr[(size_t)csr_eid[p] * 16 + lane];
    aggE[(size_t)node * 16 + lane] = acc;
}

// ---------------- fused pool + VN MLP: vn += relu(relu(pool@W0+b0)@W1+b1) ----------------
__global__ __launch_bounds__(128) void poolvn_k(
    const short* __restrict__ Xh, const short* __restrict__ Xl, const int* __restrict__ gstart,
    const float* __restrict__ W0, const float* __restrict__ b0,
    const float* __restrict__ W1, const float* __restrict__ b1,
    float* __restrict__ vn)
{
    __shared__ float4 red[128];
    __shared__ float p[128], q[128];
    const int g = blockIdx.x, t = threadIdx.x;
    const int c = t & 31, rr = t >> 5;
    const int s = gstart[g], e = gstart[g + 1];
    const short4* xh4 = (const short4*)Xh;
    const short4* xl4 = (const short4*)Xl;
    float4 a = make_float4(0.f, 0.f, 0.f, 0.f);
    for (int i = s + rr; i < e; i += 4) {
        short4 hv = xh4[(size_t)i * 32 + c];
        short4 lv = xl4[(size_t)i * 32 + c];
        a.x += bf2f(hv.x) + bf2f(lv.x);
        a.y += bf2f(hv.y) + bf2f(lv.y);
        a.z += bf2f(hv.z) + bf2f(lv.z);
        a.w += bf2f(hv.w) + bf2f(lv.w);
    }
    red[t] = a;
    __syncthreads();
    if (t < 32) {
        float4 a0 = red[t], a1 = red[t + 32], a2 = red[t + 64], a3 = red[t + 96];
        float cnt = (float)(e - s);
        if (cnt < 1.f) cnt = 1.f;
        float inv = 1.f / cnt;
        float4 o;
        o.x = (a0.x + a1.x + a2.x + a3.x) * inv;
        o.y = (a0.y + a1.y + a2.y + a3.y) * inv;
        o.z = (a0.z + a1.z + a2.z + a3.z) * inv;
        o.w = (a0.w + a1.w + a2.w + a3.w) * inv;
        ((float4*)p)[t] = o;
    }
    __syncthreads();
    float acc0 = b0[t];
    for (int k = 0; k < 128; ++k) acc0 = fmaf(p[k], W0[k * 128 + t], acc0);
    q[t] = fmaxf(acc0, 0.f);
    __syncthreads();
    float acc1 = b1[t];
    for (int k = 0; k < 128; ++k) acc1 = fmaf(q[k], W1[k * 128 + t], acc1);
    vn[g * 128 + t] += fmaxf(acc1, 0.f);
}

// ---------------- fused final pool + classifier ----------------
__global__ __launch_bounds__(128) void poolfc_k(
    const short* __restrict__ Xh, const short* __restrict__ Xl, const int* __restrict__ gstart,
    const float* __restrict__ W, const float* __restrict__ b,
    float* __restrict__ out)
{
    __shared__ float4 red[128];
    __shared__ float p[128];
    const int g = blockIdx.x, t = threadIdx.x;
    const int c = t & 31, rr = t >> 5;
    const int s = gstart[g], e = gstart[g + 1];
    const short4* xh4 = (const short4*)Xh;
    const short4* xl4 = (const short4*)Xl;
    float4 a = make_float4(0.f, 0.f, 0.f, 0.f);
    for (int i = s + rr; i < e; i += 4) {
        short4 hv = xh4[(size_t)i * 32 + c];
        short4 lv = xl4[(size_t)i * 32 + c];
        a.x += bf2f(hv.x) + bf2f(lv.x);
        a.y += bf2f(hv.y) + bf2f(lv.y);
        a.z += bf2f(hv.z) + bf2f(lv.z);
        a.w += bf2f(hv.w) + bf2f(lv.w);
    }
    red[t] = a;
    __syncthreads();
    if (t < 32) {
        float4 a0 = red[t], a1 = red[t + 32], a2 = red[t + 64], a3 = red[t + 96];
        float cnt = (float)(e - s);
        if (cnt < 1.f) cnt = 1.f;
        float inv = 1.f / cnt;
        float4 o;
        o.x = (a0.x + a1.x + a2.x + a3.x) * inv;
        o.y = (a0.y + a1.y + a2.y + a3.y) * inv;
        o.z = (a0.z + a1.z + a2.z + a3.z) * inv;
        o.w = (a0.w + a1.w + a2.w + a3.w) * inv;
        ((float4*)p)[t] = o;
    }
    __syncthreads();
    float acc = b[t];
    for (int k = 0; k < 128; ++k) acc = fmaf(p[k], W[k * 128 + t], acc);
    out[g * 128 + t] = acc;
}

// ---------------- CSR build helpers ----------------
__global__ void histp_k(const int* __restrict__ idx, int n, int* __restrict__ cntp)
{
    int i = blockIdx.x * 256 + threadIdx.x;
    if (i < n) atomicAdd(&cntp[(blockIdx.x & 3) * NN16 + (idx[i] << 4)], 1);
}

__global__ void scan_deg_k(const int* __restrict__ degp, int n, int* __restrict__ out, int* __restrict__ bsum)
{
    __shared__ int s[256];
    int gid = blockIdx.x * 256 + threadIdx.x;
    int v = 0;
    if (gid < n) {
        int o = gid << 4;
        v = degp[o] + degp[NN16 + o] + degp[2 * NN16 + o] + degp[3 * NN16 + o];
    }
    s[threadIdx.x] = v;
    __syncthreads();
    for (int off = 1; off < 256; off <<= 1) {
        int t = (threadIdx.x >= off) ? s[threadIdx.x - off] : 0;
        __syncthreads();
        s[threadIdx.x] += t;
        __syncthreads();
    }
    int incl = s[threadIdx.x];
    if (gid < n) out[gid] = incl - v;
    if (bsum != nullptr && threadIdx.x == 255) bsum[blockIdx.x] = incl;
}

__global__ void scan_k(const int* __restrict__ in, int n, int* __restrict__ out, int* __restrict__ bsum)
{
    __shared__ int s[256];
    int gid = blockIdx.x * 256 + threadIdx.x;
    int v = (gid < n) ? in[gid] : 0;
    s[threadIdx.x] = v;
    __syncthreads();
    for (int off = 1; off < 256; off <<= 1) {
        int t = (threadIdx.x >= off) ? s[threadIdx.x - off] : 0;
        __syncthreads();
        s[threadIdx.x] += t;
        __syncthreads();
    }
    int incl = s[threadIdx.x];
    if (gid < n) out[gid] = incl - v;
    if (bsum != nullptr && threadIdx.x == 255) bsum[blockIdx.x] = incl;
}

__global__ void addoff_k(int* __restrict__ data, const int* __restrict__ boff, int n, int total)
{
    int i = blockIdx.x * 256 + threadIdx.x;
    if (i < n) data[i] += boff[blockIdx.x];
    if (i == 0) data[n] = total;
}

__global__ void curinit_k(const int* __restrict__ rowstart, int* __restrict__ cursorp)
{
    int i = blockIdx.x * 256 + threadIdx.x;
    if (i < NN) cursorp[i << 4] = rowstart[i];
}

__global__ void fill_k(const int* __restrict__ dst, const int* __restrict__ src, int n,
                       int* __restrict__ cursorp, int* __restrict__ csr_eid, int* __restrict__ csr_src)
{
    int e = blockIdx.x * 256 + threadIdx.x;
    if (e < n) {
        int slot = atomicAdd(&cursorp[dst[e] << 4], 1);
        csr_eid[slot] = e;
        csr_src[slot] = src[e];
    }
}

__global__ void gstart_k(const int* __restrict__ batch, int* __restrict__ gstart)
{
    int b = blockIdx.x * 64 + threadIdx.x;
    if (b > BB) return;
    if (b == BB) { gstart[BB] = NN; return; }
    int lo = 0, hi = NN;
    while (lo < hi) {
        int mid = (lo + hi) >> 1;
        if (batch[mid] < b) lo = mid + 1; else hi = mid;
    }
    gstart[b] = lo;
}

__global__ void vninit_k(const float* __restrict__ vninit, float* __restrict__ vn)
{
    int i = blockIdx.x * 256 + threadIdx.x;
    vn[i] = vninit[i & 127];
}

// ---------------- Launch ----------------
extern "C" void kernel_launch(void* const* d_in, const int* in_sizes, int n_in,
                              void* d_out, int out_size, void* d_ws, size_t ws_size,
                              hipStream_t stream)
{
    (void)in_sizes; (void)n_in; (void)out_size; (void)ws_size;
    const float* x       = (const float*)d_in[0];
    const float* eattr   = (const float*)d_in[1];
    const float* node_W  = (const float*)d_in[2];
    const float* node_b  = (const float*)d_in[3];
    const float* edge_W  = (const float*)d_in[4];
    const float* edge_b  = (const float*)d_in[5];
    const float* mlp1_W  = (const float*)d_in[6];
    const float* mlp1_b  = (const float*)d_in[7];
    const float* mlp2_W  = (const float*)d_in[8];
    const float* mlp2_b  = (const float*)d_in[9];
    const float* vn_w0   = (const float*)d_in[10];
    const float* vn_b0   = (const float*)d_in[11];
    const float* vn_w1   = (const float*)d_in[12];
    const float* vn_b1   = (const float*)d_in[13];
    const float* fc_W    = (const float*)d_in[14];
    const float* fc_b    = (const float*)d_in[15];
    const float* vn_init = (const float*)d_in[16];
    const int*   eidx    = (const int*)d_in[17];
    const int*   batch   = (const int*)d_in[18];
    const int* srcv = eidx;
    const int* dstv = eidx + EE;

    char* wp = (char*)d_ws;
    auto alloc = [&](size_t bytes) -> void* {
        void* p = (void*)wp;
        wp += (bytes + 255) & ~(size_t)255;
        return p;
    };
    short* X0h    = (short*)alloc((size_t)NN * HH * 2);
    short* X0l    = (short*)alloc((size_t)NN * HH * 2);
    short* Xh     = (short*)alloc((size_t)NN * HH * 2);
    short* Xl     = (short*)alloc((size_t)NN * HH * 2);
    short* Agh    = (short*)alloc((size_t)NN * HH * 2);
    short* Agl    = (short*)alloc((size_t)NN * HH * 2);
    _Float16* h16 = (_Float16*)alloc((size_t)NN * HH * 2);
    float* aggE   = (float*)alloc((size_t)NN * EDD * 4);
    float* vn     = (float*)alloc((size_t)BB * HH * 4);
    int* degp     = (int*)alloc((size_t)4 * NN16 * 4);
    int* rowstart = (int*)alloc((size_t)(NN + 1) * 4);
    int* cursorp  = (int*)alloc((size_t)NN16 * 4);
    int* csr_eid  = (int*)alloc((size_t)EE * 4);
    int* csr_src  = (int*)alloc((size_t)EE * 4);
    int* bsum     = (int*)alloc(256 * 4);
    int* boff     = (int*)alloc(256 * 4);
    int* gstart   = (int*)alloc((size_t)(BB + 1) * 4);
    short* WtN_h  = (short*)alloc((size_t)5 * 16384 * 2);
    short* WtN_l  = (short*)alloc((size_t)5 * 16384 * 2);
    short* Wt1_h  = (short*)alloc((size_t)5 * 16384 * 2);
    short* Wt1_l  = (short*)alloc((size_t)5 * 16384 * 2);
    short* Wt2_h  = (short*)alloc((size_t)5 * 16384 * 2);
    short* Wt2_l  = (short*)alloc((size_t)5 * 16384 * 2);

    hipMemsetAsync(degp, 0, (size_t)4 * NN16 * 4, stream);

    histp_k<<<(EE + 255) / 256, 256, 0, stream>>>(dstv, EE, degp);

    const int NB1 = (NN + 255) / 256;
    scan_deg_k<<<NB1, 256, 0, stream>>>(degp, NN, rowstart, bsum);
    scan_k<<<1, 256, 0, stream>>>(bsum, NB1, boff, nullptr);
    addoff_k<<<NB1, 256, 0, stream>>>(rowstart, boff, NN, EE);
    curinit_k<<<NB1, 256, 0, stream>>>(rowstart, cursorp);
    fill_k<<<(EE + 255) / 256, 256, 0, stream>>>(dstv, srcv, EE, cursorp, csr_eid, csr_src);

    gstart_k<<<5, 64, 0, stream>>>(batch, gstart);

    aggE_k<<<(NN + 15) / 16, 256, 0, stream>>>(eattr, rowstart, csr_eid, aggE, NN);
    vninit_k<<<(BB * HH) / 256, 256, 0, stream>>>(vn_init, vn);
    xprep_k<<<(NN * 32 + 255) / 256, 256, 0, stream>>>(x, X0h, X0l);

    wprep_k<<<(5 * 16384 + 255) / 256, 256, 0, stream>>>(node_W, WtN_h, WtN_l, 5 * 16384);
    wprep_k<<<(5 * 16384 + 255) / 256, 256, 0, stream>>>(mlp1_W, Wt1_h, Wt1_l, 5 * 16384);
    wprep_k<<<(5 * 16384 + 255) / 256, 256, 0, stream>>>(mlp2_W, Wt2_h, Wt2_l, 5 * 16384);

    const int GN = (NN + 63) / 64;
    const short* xinh = X0h;
    const short* xinl = X0l;
    for (int l = 0; l < LL; ++l) {
        gemm_node_k<<<GN, 256, 0, stream>>>(xinh, xinl,
                                            WtN_h + (size_t)l * 16384, WtN_l + (size_t)l * 16384,
                                            node_b + (size_t)l * HH, h16, NN, vn, batch);
        aggregate_k<<<(NN + 7) / 8, 256, 0, stream>>>(h16, aggE, edge_W + (size_t)l * EDD * HH,
                                                      edge_b + (size_t)l * HH, rowstart, csr_src, Agh, Agl, NN);
        gemm_mlp_k<<<GN, 256, 0, stream>>>(Agh, Agl,
                                           Wt1_h + (size_t)l * 16384, Wt1_l + (size_t)l * 16384, mlp1_b + (size_t)l * HH,
                                           Wt2_h + (size_t)l * 16384, Wt2_l + (size_t)l * 16384, mlp2_b + (size_t)l * HH,
                                           Xh, Xl, NN);
        poolvn_k<<<BB, 128, 0, stream>>>(Xh, Xl, gstart, vn_w0, vn_b0, vn_w1, vn_b1, vn);
        xinh = Xh; xinl = Xl;
    }
    poolfc_k<<<BB, 128, 0, stream>>>(Xh, Xl, gstart, fc_W, fc_b, (float*)d_out);
}

// Round 6
// 638.381 us; speedup vs baseline: 3.4366x; 1.1413x over previous
//
#include <hip/hip_runtime.h>

#define NN 50000
#define EE 600000
#define HH 128
#define EDD 16
#define BB 256
#define LL 5
#define NN16 (NN * 16)

typedef float f32x4 __attribute__((ext_vector_type(4)));
typedef _Float16 f16x4 __attribute__((ext_vector_type(4)));
typedef _Float16 f16x8 __attribute__((ext_vector_type(8)));

// ---------------- Weight prep: W[mat][k][n] fp32 -> frag-ordered fp16 hi/lo ----------------
// frag order: idx = ((ntw*4 + ks)*64 + lane)*8 + j ; n = (ntw>>1)*32 + (ntw&1)*16 + lm ; k = ks*32 + quad*8 + j
__global__ __launch_bounds__(256) void wprep_k(const float* __restrict__ W,
    _Float16* __restrict__ Wh, _Float16* __restrict__ Wl, int total)
{
    int idx = blockIdx.x * 256 + threadIdx.x;
    if (idx >= total) return;
    int mat = idx >> 14;
    int r = idx & 16383;
    int j = r & 7, lane = (r >> 3) & 63, ks = (r >> 9) & 3, ntw = (r >> 11) & 7;
    int lm = lane & 15, quad = lane >> 4;
    int n = (ntw >> 1) * 32 + (ntw & 1) * 16 + lm;
    int k = ks * 32 + quad * 8 + j;
    float w = W[(mat << 14) + (k << 7) + n];
    _Float16 h = (_Float16)w;
    Wh[idx] = h;
    Wl[idx] = (_Float16)(w - (float)h);
}

// ---------------- x -> fp16 (one-time) ----------------
__global__ __launch_bounds__(256) void xprep_k(const float* __restrict__ x,
    _Float16* __restrict__ X)
{
    int i = blockIdx.x * 256 + threadIdx.x;   // over NN*32 float4s
    if (i >= NN * 32) return;
    float4 v = ((const float4*)x)[i];
    f16x4 o;
    o[0] = (_Float16)v.x; o[1] = (_Float16)v.y; o[2] = (_Float16)v.z; o[3] = (_Float16)v.w;
    ((f16x4*)X)[i] = o;
}

// ---------------- shared GEMM helpers ----------------
__device__ __forceinline__ void stage_A16(const _Float16* __restrict__ Ag, int M, int brow,
    int tid, _Float16* __restrict__ As)
{
    const int r = tid >> 2, cg = tid & 3;
    const int grow = brow + r;
    _Float16* p = As + r * 136 + cg * 32;
    if (grow < M) {
        const f16x8* s = (const f16x8*)(Ag + (size_t)grow * 128 + cg * 32);
#pragma unroll
        for (int i = 0; i < 4; ++i) ((f16x8*)p)[i] = s[i];
    } else {
        f16x8 z = (f16x8)(_Float16)0;
#pragma unroll
        for (int i = 0; i < 4; ++i) ((f16x8*)p)[i] = z;
    }
}

// one full K=128 pass: acc[mt][nt] += A(LDS,fp16) x (Wh+Wl)(frag-ordered global, L2-hot)
__device__ __forceinline__ void mfma_stage16(
    const _Float16* __restrict__ As,
    const _Float16* __restrict__ Wh, const _Float16* __restrict__ Wl,
    int wn, int lm, int quad, int lane, f32x4 acc[4][2])
{
    f16x8 Bh[2][4], Bl[2][4];
#pragma unroll
    for (int nt = 0; nt < 2; ++nt)
#pragma unroll
        for (int ks = 0; ks < 4; ++ks) {
            int fi = ((((wn * 2 + nt) * 4) + ks) * 64 + lane) * 8;
            Bh[nt][ks] = *(const f16x8*)(Wh + fi);
            Bl[nt][ks] = *(const f16x8*)(Wl + fi);
        }
#pragma unroll
    for (int ks = 0; ks < 4; ++ks) {
        f16x8 a[4];
#pragma unroll
        for (int mt = 0; mt < 4; ++mt) {
            int off = (mt * 16 + lm) * 136 + ks * 32 + quad * 8;
            a[mt] = *(const f16x8*)(As + off);
        }
#pragma unroll
        for (int mt = 0; mt < 4; ++mt)
#pragma unroll
            for (int nt = 0; nt < 2; ++nt) {
                acc[mt][nt] = __builtin_amdgcn_mfma_f32_16x16x32_f16(a[mt], Bh[nt][ks], acc[mt][nt], 0, 0, 0);
                acc[mt][nt] = __builtin_amdgcn_mfma_f32_16x16x32_f16(a[mt], Bl[nt][ks], acc[mt][nt], 0, 0, 0);
            }
    }
}

__device__ __forceinline__ void store_f16(const _Float16* __restrict__ Fo,
    _Float16* __restrict__ out, int M, int brow, int tid)
{
    const int r = tid >> 2, cg = tid & 3;
    const int grow = brow + r;
    if (grow >= M) return;
    const f16x8* src = (const f16x8*)(Fo + r * 136 + cg * 32);
    f16x8* dst = (f16x8*)(out + (size_t)grow * 128 + cg * 32);
#pragma unroll
    for (int i = 0; i < 4; ++i) dst[i] = src[i];
}

// ---------------- node encode: h = fp16(A @ W + b + vn[batch]) ----------------
__global__ __launch_bounds__(256) void gemm_node_k(
    const _Float16* __restrict__ Ag,
    const _Float16* __restrict__ Wh, const _Float16* __restrict__ Wl,
    const float* __restrict__ bias, _Float16* __restrict__ out, int M,
    const float* __restrict__ vn, const int* __restrict__ batch)
{
    __shared__ __align__(16) _Float16 smem[64 * 136];
    const int tid = threadIdx.x, brow = blockIdx.x * 64;

    stage_A16(Ag, M, brow, tid, smem);
    __syncthreads();

    const int lane = tid & 63, wn = tid >> 6, lm = lane & 15, quad = lane >> 4;
    f32x4 acc[4][2];
#pragma unroll
    for (int mt = 0; mt < 4; ++mt) { acc[mt][0] = (f32x4)(0.f); acc[mt][1] = (f32x4)(0.f); }
    mfma_stage16(smem, Wh, Wl, wn, lm, quad, lane, acc);
    __syncthreads();

    const int colb = wn * 32 + lm;
    const float b0 = bias[colb], b1 = bias[colb + 16];
#pragma unroll
    for (int mt = 0; mt < 4; ++mt) {
#pragma unroll
        for (int r = 0; r < 4; ++r) {
            int trow = mt * 16 + quad * 4 + r;
            int grow = brow + trow;
            int bg = batch[grow < M ? grow : M - 1];
            const float* vrow = vn + (size_t)bg * 128;
            smem[trow * 136 + colb]      = (_Float16)(acc[mt][0][r] + b0 + vrow[colb]);
            smem[trow * 136 + colb + 16] = (_Float16)(acc[mt][1][r] + b1 + vrow[colb + 16]);
        }
    }
    __syncthreads();
    store_f16(smem, out, M, brow, tid);
}

// ---------------- fused MLP: X = fp16(relu(relu(A@W1+b1)@W2+b2)) ----------------
__global__ __launch_bounds__(256) void gemm_mlp_k(
    const _Float16* __restrict__ Ag,
    const _Float16* __restrict__ W1h, const _Float16* __restrict__ W1l, const float* __restrict__ b1,
    const _Float16* __restrict__ W2h, const _Float16* __restrict__ W2l, const float* __restrict__ b2,
    _Float16* __restrict__ X, int M)
{
    __shared__ __align__(16) _Float16 smem[64 * 136];
    const int tid = threadIdx.x, brow = blockIdx.x * 64;

    stage_A16(Ag, M, brow, tid, smem);
    __syncthreads();

    const int lane = tid & 63, wn = tid >> 6, lm = lane & 15, quad = lane >> 4;
    const int colb = wn * 32 + lm;

    f32x4 acc[4][2];
#pragma unroll
    for (int mt = 0; mt < 4; ++mt) { acc[mt][0] = (f32x4)(0.f); acc[mt][1] = (f32x4)(0.f); }
    mfma_stage16(smem, W1h, W1l, wn, lm, quad, lane, acc);
    __syncthreads();

    // epilogue-1: bias+relu -> fp16 back into the A tile
    {
        const float c0 = b1[colb], c1 = b1[colb + 16];
#pragma unroll
        for (int mt = 0; mt < 4; ++mt) {
#pragma unroll
            for (int r = 0; r < 4; ++r) {
                int trow = mt * 16 + quad * 4 + r;
                smem[trow * 136 + colb]      = (_Float16)fmaxf(acc[mt][0][r] + c0, 0.f);
                smem[trow * 136 + colb + 16] = (_Float16)fmaxf(acc[mt][1][r] + c1, 0.f);
            }
        }
    }
    __syncthreads();

#pragma unroll
    for (int mt = 0; mt < 4; ++mt) { acc[mt][0] = (f32x4)(0.f); acc[mt][1] = (f32x4)(0.f); }
    mfma_stage16(smem, W2h, W2l, wn, lm, quad, lane, acc);
    __syncthreads();

    const float d0 = b2[colb], d1 = b2[colb + 16];
#pragma unroll
    for (int mt = 0; mt < 4; ++mt) {
#pragma unroll
        for (int r = 0; r < 4; ++r) {
            int trow = mt * 16 + quad * 4 + r;
            smem[trow * 136 + colb]      = (_Float16)fmaxf(acc[mt][0][r] + d0, 0.f);
            smem[trow * 136 + colb + 16] = (_Float16)fmaxf(acc[mt][1][r] + d1, 0.f);
        }
    }
    __syncthreads();
    store_f16(smem, X, M, brow, tid);
}

// ---------------- Edge aggregation: fp16 gather-sum + per-node edge term -> fp16 ----------------
__global__ __launch_bounds__(256) void aggregate_k(
    const _Float16* __restrict__ h, const float* __restrict__ aggE,
    const float* __restrict__ eW, const float* __restrict__ eb,
    const int* __restrict__ rowstart, const int* __restrict__ csr_src,
    _Float16* __restrict__ Ag, int n)
{
    __shared__ float eWs[16 * 128];
    __shared__ float ebs[128];
    const int tid = threadIdx.x;
#pragma unroll
    for (int t = 0; t < 2; ++t) {
        int li = (tid + t * 256) * 4;
        *(float4*)(&eWs[li]) = *(const float4*)(eW + li);
    }
    if (tid < 32) *(float4*)(&ebs[tid * 4]) = *(const float4*)(eb + tid * 4);
    __syncthreads();

    const int lane = tid & 31;
    const int node = blockIdx.x * 8 + (tid >> 5);
    if (node >= n) return;
    const int s = rowstart[node], e = rowstart[node + 1];
    const f16x4* h4 = (const f16x4*)h;

    float4 acc = make_float4(0.f, 0.f, 0.f, 0.f);
    int p = s;
    for (; p + 4 <= e; p += 4) {
        int s0 = csr_src[p], s1 = csr_src[p + 1], s2 = csr_src[p + 2], s3 = csr_src[p + 3];
        f16x4 v0 = h4[(size_t)s0 * 32 + lane];
        f16x4 v1 = h4[(size_t)s1 * 32 + lane];
        f16x4 v2 = h4[(size_t)s2 * 32 + lane];
        f16x4 v3 = h4[(size_t)s3 * 32 + lane];
        acc.x += (float)v0[0] + (float)v1[0] + (float)v2[0] + (float)v3[0];
        acc.y += (float)v0[1] + (float)v1[1] + (float)v2[1] + (float)v3[1];
        acc.z += (float)v0[2] + (float)v1[2] + (float)v2[2] + (float)v3[2];
        acc.w += (float)v0[3] + (float)v1[3] + (float)v2[3] + (float)v3[3];
    }
    for (; p < e; ++p) {
        f16x4 v = h4[(size_t)csr_src[p] * 32 + lane];
        acc.x += (float)v[0]; acc.y += (float)v[1]; acc.z += (float)v[2]; acc.w += (float)v[3];
    }

    const float degf = (float)(e - s);
    const float* ae = aggE + (size_t)node * 16;
    const float4 b4 = *(const float4*)(&ebs[lane * 4]);
    float4 et = make_float4(degf * b4.x, degf * b4.y, degf * b4.z, degf * b4.w);
#pragma unroll
    for (int k = 0; k < 16; ++k) {
        float a = ae[k];
        float4 w = *(const float4*)(&eWs[k * 128 + lane * 4]);
        et.x = fmaf(a, w.x, et.x);
        et.y = fmaf(a, w.y, et.y);
        et.z = fmaf(a, w.z, et.z);
        et.w = fmaf(a, w.w, et.w);
    }
    acc.x += et.x; acc.y += et.y; acc.z += et.z; acc.w += et.w;

    f16x4 o;
    o[0] = (_Float16)acc.x; o[1] = (_Float16)acc.y; o[2] = (_Float16)acc.z; o[3] = (_Float16)acc.w;
    ((f16x4*)Ag)[(size_t)node * 32 + lane] = o;
}

// ---------------- aggE[n,16] = sum of eattr over in-edges ----------------
__global__ __launch_bounds__(256) void aggE_k(
    const float* __restrict__ eattr, const int* __restrict__ rowstart,
    const int2* __restrict__ csr_pair, float* __restrict__ aggE, int n)
{
    const int lane = threadIdx.x & 15;
    const int node = blockIdx.x * 16 + (threadIdx.x >> 4);
    if (node >= n) return;
    const int s = rowstart[node], e = rowstart[node + 1];
    float acc = 0.f;
    for (int p = s; p < e; ++p)
        acc += eattr[(size_t)csr_pair[p].y * 16 + lane];
    aggE[(size_t)node * 16 + lane] = acc;
}

// ---------------- fused pool + VN MLP ----------------
__global__ __launch_bounds__(128) void poolvn_k(
    const _Float16* __restrict__ X, const int* __restrict__ gstart,
    const float* __restrict__ W0, const float* __restrict__ b0,
    const float* __restrict__ W1, const float* __restrict__ b1,
    float* __restrict__ vn)
{
    __shared__ float4 red[128];
    __shared__ float p[128], q[128];
    const int g = blockIdx.x, t = threadIdx.x;
    const int c = t & 31, rr = t >> 5;
    const int s = gstart[g], e = gstart[g + 1];
    const f16x4* x4 = (const f16x4*)X;
    float4 a = make_float4(0.f, 0.f, 0.f, 0.f);
    for (int i = s + rr; i < e; i += 4) {
        f16x4 v = x4[(size_t)i * 32 + c];
        a.x += (float)v[0]; a.y += (float)v[1]; a.z += (float)v[2]; a.w += (float)v[3];
    }
    red[t] = a;
    __syncthreads();
    if (t < 32) {
        float4 a0 = red[t], a1 = red[t + 32], a2 = red[t + 64], a3 = red[t + 96];
        float cnt = (float)(e - s);
        if (cnt < 1.f) cnt = 1.f;
        float inv = 1.f / cnt;
        float4 o;
        o.x = (a0.x + a1.x + a2.x + a3.x) * inv;
        o.y = (a0.y + a1.y + a2.y + a3.y) * inv;
        o.z = (a0.z + a1.z + a2.z + a3.z) * inv;
        o.w = (a0.w + a1.w + a2.w + a3.w) * inv;
        ((float4*)p)[t] = o;
    }
    __syncthreads();
    float acc0 = b0[t];
    for (int k = 0; k < 128; ++k) acc0 = fmaf(p[k], W0[k * 128 + t], acc0);
    q[t] = fmaxf(acc0, 0.f);
    __syncthreads();
    float acc1 = b1[t];
    for (int k = 0; k < 128; ++k) acc1 = fmaf(q[k], W1[k * 128 + t], acc1);
    vn[g * 128 + t] += fmaxf(acc1, 0.f);
}

// ---------------- fused final pool + classifier ----------------
__global__ __launch_bounds__(128) void poolfc_k(
    const _Float16* __restrict__ X, const int* __restrict__ gstart,
    const float* __restrict__ W, const float* __restrict__ b,
    float* __restrict__ out)
{
    __shared__ float4 red[128];
    __shared__ float p[128];
    const int g = blockIdx.x, t = threadIdx.x;
    const int c = t & 31, rr = t >> 5;
    const int s = gstart[g], e = gstart[g + 1];
    const f16x4* x4 = (const f16x4*)X;
    float4 a = make_float4(0.f, 0.f, 0.f, 0.f);
    for (int i = s + rr; i < e; i += 4) {
        f16x4 v = x4[(size_t)i * 32 + c];
        a.x += (float)v[0]; a.y += (float)v[1]; a.z += (float)v[2]; a.w += (float)v[3];
    }
    red[t] = a;
    __syncthreads();
    if (t < 32) {
        float4 a0 = red[t], a1 = red[t + 32], a2 = red[t + 64], a3 = red[t + 96];
        float cnt = (float)(e - s);
        if (cnt < 1.f) cnt = 1.f;
        float inv = 1.f / cnt;
        float4 o;
        o.x = (a0.x + a1.x + a2.x + a3.x) * inv;
        o.y = (a0.y + a1.y + a2.y + a3.y) * inv;
        o.z = (a0.z + a1.z + a2.z + a3.z) * inv;
        o.w = (a0.w + a1.w + a2.w + a3.w) * inv;
        ((float4*)p)[t] = o;
    }
    __syncthreads();
    float acc = b[t];
    for (int k = 0; k < 128; ++k) acc = fmaf(p[k], W[k * 128 + t], acc);
    out[g * 128 + t] = acc;
}

// ---------------- CSR build helpers ----------------
__global__ void histp_k(const int* __restrict__ idx, int n, int* __restrict__ cntp)
{
    int i = blockIdx.x * 256 + threadIdx.x;
    if (i < n) atomicAdd(&cntp[(blockIdx.x & 3) * NN16 + (idx[i] << 4)], 1);
}

__global__ void scan_deg_k(const int* __restrict__ degp, int n, int* __restrict__ out, int* __restrict__ bsum)
{
    __shared__ int s[256];
    int gid = blockIdx.x * 256 + threadIdx.x;
    int v = 0;
    if (gid < n) {
        int o = gid << 4;
        v = degp[o] + degp[NN16 + o] + degp[2 * NN16 + o] + degp[3 * NN16 + o];
    }
    s[threadIdx.x] = v;
    __syncthreads();
    for (int off = 1; off < 256; off <<= 1) {
        int t = (threadIdx.x >= off) ? s[threadIdx.x - off] : 0;
        __syncthreads();
        s[threadIdx.x] += t;
        __syncthreads();
    }
    int incl = s[threadIdx.x];
    if (gid < n) out[gid] = incl - v;
    if (bsum != nullptr && threadIdx.x == 255) bsum[blockIdx.x] = incl;
}

__global__ void scan_k(const int* __restrict__ in, int n, int* __restrict__ out, int* __restrict__ bsum)
{
    __shared__ int s[256];
    int gid = blockIdx.x * 256 + threadIdx.x;
    int v = (gid < n) ? in[gid] : 0;
    s[threadIdx.x] = v;
    __syncthreads();
    for (int off = 1; off < 256; off <<= 1) {
        int t = (threadIdx.x >= off) ? s[threadIdx.x - off] : 0;
        __syncthreads();
        s[threadIdx.x] += t;
        __syncthreads();
    }
    int incl = s[threadIdx.x];
    if (gid < n) out[gid] = incl - v;
    if (bsum != nullptr && threadIdx.x == 255) bsum[blockIdx.x] = incl;
}

__global__ void addoff_k(int* __restrict__ data, const int* __restrict__ boff, int n, int total)
{
    int i = blockIdx.x * 256 + threadIdx.x;
    if (i < n) data[i] += boff[blockIdx.x];
    if (i == 0) data[n] = total;
}

__global__ void curinit_k(const int* __restrict__ rowstart, int* __restrict__ cursorp)
{
    int i = blockIdx.x * 256 + threadIdx.x;
    if (i < NN) cursorp[i << 4] = rowstart[i];
}

__global__ void fill_k(const int* __restrict__ dst, const int* __restrict__ src, int n,
                       int* __restrict__ cursorp, int2* __restrict__ csr_pair)
{
    int e = blockIdx.x * 256 + threadIdx.x;
    if (e < n) {
        int slot = atomicAdd(&cursorp[dst[e] << 4], 1);
        int2 pr; pr.x = src[e]; pr.y = e;
        csr_pair[slot] = pr;
    }
}

__global__ void split_k(const int2* __restrict__ csr_pair, int* __restrict__ csr_src, int n)
{
    int i = blockIdx.x * 256 + threadIdx.x;
    if (i < n) csr_src[i] = csr_pair[i].x;
}

__global__ void gstart_k(const int* __restrict__ batch, int* __restrict__ gstart)
{
    int b = blockIdx.x * 64 + threadIdx.x;
    if (b > BB) return;
    if (b == BB) { gstart[BB] = NN; return; }
    int lo = 0, hi = NN;
    while (lo < hi) {
        int mid = (lo + hi) >> 1;
        if (batch[mid] < b) lo = mid + 1; else hi = mid;
    }
    gstart[b] = lo;
}

__global__ void vninit_k(const float* __restrict__ vninit, float* __restrict__ vn)
{
    int i = blockIdx.x * 256 + threadIdx.x;
    vn[i] = vninit[i & 127];
}

// ---------------- Launch ----------------
extern "C" void kernel_launch(void* const* d_in, const int* in_sizes, int n_in,
                              void* d_out, int out_size, void* d_ws, size_t ws_size,
                              hipStream_t stream)
{
    (void)in_sizes; (void)n_in; (void)out_size; (void)ws_size;
    const float* x       = (const float*)d_in[0];
    const float* eattr   = (const float*)d_in[1];
    const float* node_W  = (const float*)d_in[2];
    const float* node_b  = (const float*)d_in[3];
    const float* edge_W  = (const float*)d_in[4];
    const float* edge_b  = (const float*)d_in[5];
    const float* mlp1_W  = (const float*)d_in[6];
    const float* mlp1_b  = (const float*)d_in[7];
    const float* mlp2_W  = (const float*)d_in[8];
    const float* mlp2_b  = (const float*)d_in[9];
    const float* vn_w0   = (const float*)d_in[10];
    const float* vn_b0   = (const float*)d_in[11];
    const float* vn_w1   = (const float*)d_in[12];
    const float* vn_b1   = (const float*)d_in[13];
    const float* fc_W    = (const float*)d_in[14];
    const float* fc_b    = (const float*)d_in[15];
    const float* vn_init = (const float*)d_in[16];
    const int*   eidx    = (const int*)d_in[17];
    const int*   batch   = (const int*)d_in[18];
    const int* srcv = eidx;
    const int* dstv = eidx + EE;

    char* wp = (char*)d_ws;
    auto alloc = [&](size_t bytes) -> void* {
        void* p = (void*)wp;
        wp += (bytes + 255) & ~(size_t)255;
        return p;
    };
    _Float16* X0  = (_Float16*)alloc((size_t)NN * HH * 2);
    _Float16* X   = (_Float16*)alloc((size_t)NN * HH * 2);
    _Float16* Ag  = (_Float16*)alloc((size_t)NN * HH * 2);
    _Float16* h16 = (_Float16*)alloc((size_t)NN * HH * 2);
    float* aggE   = (float*)alloc((size_t)NN * EDD * 4);
    float* vn     = (float*)alloc((size_t)BB * HH * 4);
    int* degp     = (int*)alloc((size_t)4 * NN16 * 4);
    int* rowstart = (int*)alloc((size_t)(NN + 1) * 4);
    int* cursorp  = (int*)alloc((size_t)NN16 * 4);
    int2* csr_pair= (int2*)alloc((size_t)EE * 8);
    int* csr_src  = (int*)alloc((size_t)EE * 4);
    int* bsum     = (int*)alloc(256 * 4);
    int* boff     = (int*)alloc(256 * 4);
    int* gstart   = (int*)alloc((size_t)(BB + 1) * 4);
    _Float16* WtN_h = (_Float16*)alloc((size_t)5 * 16384 * 2);
    _Float16* WtN_l = (_Float16*)alloc((size_t)5 * 16384 * 2);
    _Float16* Wt1_h = (_Float16*)alloc((size_t)5 * 16384 * 2);
    _Float16* Wt1_l = (_Float16*)alloc((size_t)5 * 16384 * 2);
    _Float16* Wt2_h = (_Float16*)alloc((size_t)5 * 16384 * 2);
    _Float16* Wt2_l = (_Float16*)alloc((size_t)5 * 16384 * 2);

    hipMemsetAsync(degp, 0, (size_t)4 * NN16 * 4, stream);

    histp_k<<<(EE + 255) / 256, 256, 0, stream>>>(dstv, EE, degp);

    const int NB1 = (NN + 255) / 256;
    scan_deg_k<<<NB1, 256, 0, stream>>>(degp, NN, rowstart, bsum);
    scan_k<<<1, 256, 0, stream>>>(bsum, NB1, boff, nullptr);
    addoff_k<<<NB1, 256, 0, stream>>>(rowstart, boff, NN, EE);
    curinit_k<<<NB1, 256, 0, stream>>>(rowstart, cursorp);
    fill_k<<<(EE + 255) / 256, 256, 0, stream>>>(dstv, srcv, EE, cursorp, csr_pair);
    split_k<<<(EE + 255) / 256, 256, 0, stream>>>(csr_pair, csr_src, EE);

    gstart_k<<<5, 64, 0, stream>>>(batch, gstart);

    aggE_k<<<(NN + 15) / 16, 256, 0, stream>>>(eattr, rowstart, csr_pair, aggE, NN);
    vninit_k<<<(BB * HH) / 256, 256, 0, stream>>>(vn_init, vn);
    xprep_k<<<(NN * 32 + 255) / 256, 256, 0, stream>>>(x, X0);

    wprep_k<<<(5 * 16384 + 255) / 256, 256, 0, stream>>>(node_W, WtN_h, WtN_l, 5 * 16384);
    wprep_k<<<(5 * 16384 + 255) / 256, 256, 0, stream>>>(mlp1_W, Wt1_h, Wt1_l, 5 * 16384);
    wprep_k<<<(5 * 16384 + 255) / 256, 256, 0, stream>>>(mlp2_W, Wt2_h, Wt2_l, 5 * 16384);

    const int GN = (NN + 63) / 64;
    const _Float16* xin = X0;
    for (int l = 0; l < LL; ++l) {
        gemm_node_k<<<GN, 256, 0, stream>>>(xin,
                                            WtN_h + (size_t)l * 16384, WtN_l + (size_t)l * 16384,
                                            node_b + (size_t)l * HH, h16, NN, vn, batch);
        aggregate_k<<<(NN + 7) / 8, 256, 0, stream>>>(h16, aggE, edge_W + (size_t)l * EDD * HH,
                                                      edge_b + (size_t)l * HH, rowstart, csr_src, Ag, NN);
        gemm_mlp_k<<<GN, 256, 0, stream>>>(Ag,
                                           Wt1_h + (size_t)l * 16384, Wt1_l + (size_t)l * 16384, mlp1_b + (size_t)l * HH,
                                           Wt2_h + (size_t)l * 16384, Wt2_l + (size_t)l * 16384, mlp2_b + (size_t)l * HH,
                                           X, NN);
        poolvn_k<<<BB, 128, 0, stream>>>(X, gstart, vn_w0, vn_b0, vn_w1, vn_b1, vn);
        xin = X;
    }
    poolfc_k<<<BB, 128, 0, stream>>>(X, gstart, fc_W, fc_b, (float*)d_out);
}